// Round 3
// baseline (199.511 us; speedup 1.0000x reference)
//
#include <hip/hip_runtime.h>
#include <stdint.h>

#define D_MODEL 1024
#define NHEAD   16
#define DK      64
#define BATCH   2
#define SEQ     2048
#define MTOT    (BATCH*SEQ)   // 4096

typedef unsigned short u16;
typedef unsigned int   u32;
typedef u16    u16x4  __attribute__((ext_vector_type(4)));
typedef u16    u16x8  __attribute__((ext_vector_type(8)));
typedef u32    u32x4  __attribute__((ext_vector_type(4)));
typedef __bf16 bf16x8 __attribute__((ext_vector_type(8)));
typedef float  f32x4  __attribute__((ext_vector_type(4)));
typedef float  f32x16 __attribute__((ext_vector_type(16)));

__device__ __forceinline__ u16 f2bf(float f) {
  union { float f; unsigned u; } v; v.f = f;
  return (u16)((v.u + 0x7fffu + ((v.u >> 16) & 1u)) >> 16);
}

__device__ __forceinline__ void gl_lds16(const void* g, void* l) {
  __builtin_amdgcn_global_load_lds((const __attribute__((address_space(1))) void*)g,
                                   (__attribute__((address_space(3))) void*)l, 16, 0, 0);
}

__device__ __forceinline__ bf16x8 ld_frag(const u16* p) {
  return __builtin_bit_cast(bf16x8, *(const u16x8*)p);
}

__device__ __forceinline__ u32 cvtpk(float lo, float hi) {
  u32 r;
  asm("v_cvt_pk_bf16_f32 %0, %1, %2" : "=v"(r) : "v"(lo), "v"(hi));
  return r;
}

// ---------------- prep: x -> bf16 ----------------
__global__ __launch_bounds__(256) void k_cvt_x(const float* __restrict__ x, u16* __restrict__ xb) {
  int i = blockIdx.x * 256 + threadIdx.x;
  const float4 v = ((const float4*)x)[i];
  u16x4 o; o[0]=f2bf(v.x); o[1]=f2bf(v.y); o[2]=f2bf(v.z); o[3]=f2bf(v.w);
  *(u16x4*)(xb + (size_t)i*4) = o;
}

// ---------------- prep: W -> W^T bf16 ----------------
__global__ __launch_bounds__(256) void k_wtrans(const float* __restrict__ wq, const float* __restrict__ wk,
                                                const float* __restrict__ wv, const float* __restrict__ wo,
                                                u16* __restrict__ wqkv_t, u16* __restrict__ wo_t) {
  __shared__ float tile[32][33];
  const int z = blockIdx.z;
  const float* src = (z==0)?wq:(z==1)?wk:(z==2)?wv:wo;
  const int kb = blockIdx.y*32, nb = blockIdx.x*32;
  const int tx = threadIdx.x & 31, ty = threadIdx.x >> 5;  // 32 x 8
  #pragma unroll
  for (int i=0;i<4;i++)
    tile[ty + i*8][tx] = src[(size_t)(kb + ty + i*8)*D_MODEL + nb + tx];
  __syncthreads();
  u16* dst = (z<3) ? (wqkv_t + (size_t)z*D_MODEL*D_MODEL) : wo_t;
  #pragma unroll
  for (int i=0;i<4;i++) {
    int n = nb + ty + i*8, k = kb + tx;
    dst[(size_t)n*D_MODEL + k] = f2bf(tile[tx][ty + i*8]);
  }
}

// ---------------- prep: pack mask to bits ----------------
__global__ __launch_bounds__(256) void k_maskpack(const int* __restrict__ mask,
                                                  unsigned long long* __restrict__ mb) {
  const int wid = blockIdx.x*4 + (threadIdx.x >> 6);   // 0..4095
  const int lane = threadIdx.x & 63;
  for (int t2 = 0; t2 < 32; ++t2) {
    int word = wid*32 + t2;                 // 0..131071
    int row = word >> 5;                    // b*SEQ + i
    int kb = word & 31;
    int m = mask[(size_t)row*SEQ + kb*64 + lane];
    unsigned long long bits = __ballot(m != 0);
    if (lane == 0) mb[word] = bits;
  }
}

// ---------------- prep: V [bh][L][64] -> Vt [bh][64][L] ----------------
__global__ __launch_bounds__(256) void k_vtrans(const u16* __restrict__ V, u16* __restrict__ Vt) {
  __shared__ u16 tile[64][72];
  const int bh = blockIdx.x >> 5;
  const int l0 = (blockIdx.x & 31) * 64;
  const int t = threadIdx.x;
  const u16* src = V + ((size_t)bh*SEQ + l0)*DK;
  #pragma unroll
  for (int j=0;j<2;j++) {
    int idx = t + j*256;                 // 0..511
    int r = idx >> 3, c8 = (idx & 7)*8;
    *(u16x8*)&tile[r][c8] = *(const u16x8*)(src + (size_t)r*DK + c8);
  }
  __syncthreads();
  u16* dst = Vt + (size_t)bh*DK*SEQ + l0;
  #pragma unroll
  for (int j=0;j<2;j++) {
    int idx = t + j*256;
    int d = idx >> 3, k8 = (idx & 7)*8;
    u16x8 o;
    #pragma unroll
    for (int e=0;e<8;e++) o[e] = tile[k8 + e][d];
    *(u16x8*)(dst + (size_t)d*SEQ + k8) = o;
  }
}

// ---------------- 128x128 MFMA GEMM, C = A @ Bt^T (+epilogue) ----------------
template<int EPI>
__global__ __launch_bounds__(256) void k_gemm(const u16* __restrict__ A, const u16* __restrict__ Bt,
                                              const int M, const int N, const int K, const int nbm,
                                              const float* __restrict__ bq, const float* __restrict__ bk,
                                              const float* __restrict__ bv,
                                              u16* __restrict__ Qo, u16* __restrict__ Ko, u16* __restrict__ Vo,
                                              const float* __restrict__ bo, float* __restrict__ out) {
  __shared__ u16 As[128*32];
  __shared__ u16 Bs[128*32];
  const int t = threadIdx.x, lane = t & 63, w = t >> 6;
  const int bm = blockIdx.x % nbm, bn = blockIdx.x / nbm;
  const int brow = bm*128, bcol = bn*128;

  const int srow = w*32 + (lane >> 2);
  const int sswz = (lane & 3) ^ ((lane >> 2) & 3);
  const u16* aS0 = A  + (size_t)(brow + srow)*K + sswz*8;
  const u16* aS1 = aS0 + (size_t)16*K;
  const u16* bS0 = Bt + (size_t)(bcol + srow)*K + sswz*8;
  const u16* bS1 = bS0 + (size_t)16*K;
  u16* aD0 = As + w*1024; u16* aD1 = aD0 + 512;
  u16* bD0 = Bs + w*1024; u16* bD1 = bD0 + 512;

  const int wr = w >> 1, wc = w & 1;
  const int slotA = (lane >> 4) ^ (lane & 3);
  const u16* aRd = As + (wr*64 + (lane & 15))*32 + slotA*8;
  const u16* bRd = Bs + (wc*64 + (lane & 15))*32 + slotA*8;

  f32x4 acc[4][4];
  #pragma unroll
  for (int i=0;i<4;i++)
    #pragma unroll
    for (int j=0;j<4;j++) acc[i][j] = (f32x4){0.f,0.f,0.f,0.f};

  for (int kt = 0; kt < K; kt += 32) {
    gl_lds16(aS0 + kt, aD0);
    gl_lds16(aS1 + kt, aD1);
    gl_lds16(bS0 + kt, bD0);
    gl_lds16(bS1 + kt, bD1);
    __syncthreads();
    bf16x8 af[4], bfr[4];
    #pragma unroll
    for (int m=0;m<4;m++) af[m] = ld_frag(aRd + m*512);
    #pragma unroll
    for (int n=0;n<4;n++) bfr[n] = ld_frag(bRd + n*512);
    #pragma unroll
    for (int m=0;m<4;m++)
      #pragma unroll
      for (int n=0;n<4;n++)
        acc[m][n] = __builtin_amdgcn_mfma_f32_16x16x32_bf16(af[m], bfr[n], acc[m][n], 0,0,0);
    __syncthreads();
  }

  const int orow = brow + wr*64 + (lane >> 4)*4;
  const int ocol = bcol + wc*64 + (lane & 15);
  if (EPI == 0) {
    const int mat = ocol >> 10;
    const float* bias = (mat==0) ? bq : (mat==1) ? bk : bv;
    u16* outp = (mat==0) ? Qo : (mat==1) ? Ko : Vo;
    // fold 1/sqrt(dk) AND log2(e) into Q so attention softmax runs in exp2 domain
    const float scal = (mat==0) ? 0.125f*1.4426950408889634f : 1.0f;
    #pragma unroll
    for (int m=0;m<4;m++) {
      #pragma unroll
      for (int n=0;n<4;n++) {
        int col = ocol + n*16;
        int c = col & 1023;
        float bb = bias[c];
        int h = c >> 6, d = c & 63;
        #pragma unroll
        for (int j=0;j<4;j++) {
          int row = orow + m*16 + j;
          int b = row >> 11, l = row & 2047;
          float v = (acc[m][n][j] + bb) * scal;
          outp[(((size_t)(b*NHEAD + h)*SEQ + l) << 6) + d] = f2bf(v);
        }
      }
    }
  } else {
    #pragma unroll
    for (int m=0;m<4;m++)
      #pragma unroll
      for (int n=0;n<4;n++) {
        int col = ocol + n*16;
        float bb = bo[col];
        #pragma unroll
        for (int j=0;j<4;j++) {
          int row = orow + m*16 + j;
          out[(size_t)row*N + col] = acc[m][n][j] + bb;
        }
      }
  }
}

// ---------------- flash attention, 32x32 swapped + dbuf + MFMA l-sum + defer-max ----
__global__ __launch_bounds__(256) void k_attn(const u16* __restrict__ Q, const u16* __restrict__ K,
                                              const u16* __restrict__ Vt,
                                              const unsigned long long* __restrict__ MB,
                                              u16* __restrict__ AO) {
  __shared__ u16 Ks[2][64*64];   // [key][dk], slot-swizzled: phys = slot ^ (key&7)
  __shared__ u16 Vs[2][64*64];   // [d][key],  slot-swizzled: phys = slot ^ (d&7)
  const int t = threadIdx.x, lane = t & 63, w = t >> 6;
  // XCD-aware bijective swizzle: 512 blocks = 8 XCD x 64; XCD x gets bh 4x..4x+3
  const int bid = blockIdx.x;
  const int swz = (bid & 7)*64 + (bid >> 3);
  const int bh = swz >> 4;
  const int q0 = (swz & 15) * 128;
  const int b = bh >> 4, h = bh & 15;
  const int lq = lane & 31, hi = lane >> 5, l7 = lane & 7;

  const int qg = q0 + w*32 + lq;
  const u16* qp = Q + ((size_t)bh*SEQ + qg)*DK + hi*8;
  bf16x8 qf[4];
  #pragma unroll
  for (int ks=0;ks<4;ks++) qf[ks] = ld_frag(qp + ks*16);

  // staging: wave w stages rows w*16..w*16+15 of K tile and of V^T tile
  const int srow = w*16 + (lane >> 3);
  const int sswz = l7 ^ ((lane >> 3) & 7);        // pre-swizzled global source
  const u16* kSb = K  + ((size_t)bh*SEQ + srow)*DK + sswz*8;
  const u16* vSb = Vt + ((size_t)bh*DK + srow)*SEQ + sswz*8;

  u16x8 ones8;
  #pragma unroll
  for (int i=0;i<8;i++) ones8[i] = 0x3F80;        // bf16 1.0
  const bf16x8 ones = __builtin_bit_cast(bf16x8, ones8);

  f32x16 o0 = 0.f, o1 = 0.f, lacc = 0.f;
  float m_run = -1e30f;
  const unsigned long long* mbp = MB + ((size_t)b*SEQ + qg)*32;

  #define NT (SEQ/64)
  #define STAGE(buf, tile) do {                                   \
    const u16* kp_ = kSb + (size_t)(tile)*64*DK;                  \
    const u16* vp_ = vSb + (tile)*64;                             \
    u16* kd_ = &Ks[buf][w*1024];                                  \
    u16* vd_ = &Vs[buf][w*1024];                                  \
    gl_lds16(kp_, kd_); gl_lds16(kp_ + 8*DK, kd_ + 512);          \
    gl_lds16(vp_, vd_); gl_lds16(vp_ + 8*SEQ, vd_ + 512);         \
  } while (0)

  STAGE(0, 0);
  asm volatile("s_waitcnt vmcnt(0)" ::: "memory");
  __builtin_amdgcn_s_barrier();

  for (int kt = 0; kt < NT; ++kt) {
    const int cur = kt & 1;
    if (kt + 1 < NT) STAGE(cur ^ 1, kt + 1);     // prefetch next tile (in flight across compute)

    // ---- S^T: 2 key-tiles of 32 ----
    f32x16 s0 = 0.f, s1 = 0.f;
    __builtin_amdgcn_s_setprio(1);
    #pragma unroll
    for (int ks=0;ks<4;ks++) {
      const int ph = (ks*2 + hi) ^ l7;
      bf16x8 kf0 = ld_frag(&Ks[cur][lq*64 + ph*8]);
      bf16x8 kf1 = ld_frag(&Ks[cur][(32+lq)*64 + ph*8]);
      s0 = __builtin_amdgcn_mfma_f32_32x32x16_bf16(kf0, qf[ks], s0, 0,0,0);
      s1 = __builtin_amdgcn_mfma_f32_32x32x16_bf16(kf1, qf[ks], s1, 0,0,0);
    }
    __builtin_amdgcn_s_setprio(0);

    unsigned long long mb = mbp[kt];
    if (!__all(mb == ~0ull)) {
      #pragma unroll
      for (int r=0;r<16;r++) {
        int kl = (r&3) + 8*(r>>2) + 4*hi;
        if (!((mb >> kl) & 1ull)) s0[r] = -1e9f;
        if (!((mb >> (kl+32)) & 1ull)) s1[r] = -1e9f;
      }
    }

    // ---- online softmax, defer-max (THR=8 in exp2 domain) ----
    float mx = -1e30f;
    #pragma unroll
    for (int r=0;r<16;r++) mx = fmaxf(fmaxf(mx, s0[r]), s1[r]);   // v_max3 chain
    mx = fmaxf(mx, __shfl_xor(mx, 32));
    if (!__all(mx <= m_run + 8.0f)) {
      float m_new = fmaxf(m_run, mx);
      float corr = __builtin_amdgcn_exp2f(m_run - m_new);
      lacc[0] *= corr;
      #pragma unroll
      for (int r=0;r<16;r++) { o0[r] *= corr; o1[r] *= corr; }
      m_run = m_new;
    }
    #pragma unroll
    for (int r=0;r<16;r++) {
      s0[r] = __builtin_amdgcn_exp2f(s0[r] - m_run);
      s1[r] = __builtin_amdgcn_exp2f(s1[r] - m_run);
    }

    // ---- P -> bf16 PA frags (cvt_pk + permlane32_swap); PV + MFMA l-sum ----
    #pragma unroll
    for (int kt2=0;kt2<2;kt2++) {
      const f32x16& sv = kt2 ? s1 : s0;
      u32 w0 = cvtpk(sv[0],  sv[1]),  w1 = cvtpk(sv[2],  sv[3]);
      u32 w2 = cvtpk(sv[4],  sv[5]),  w3 = cvtpk(sv[6],  sv[7]);
      u32 w4 = cvtpk(sv[8],  sv[9]),  w5 = cvtpk(sv[10], sv[11]);
      u32 w6 = cvtpk(sv[12], sv[13]), w7 = cvtpk(sv[14], sv[15]);
      asm volatile("v_permlane32_swap_b32 %0, %1" : "+v"(w0), "+v"(w2));
      asm volatile("v_permlane32_swap_b32 %0, %1" : "+v"(w1), "+v"(w3));
      asm volatile("v_permlane32_swap_b32 %0, %1" : "+v"(w4), "+v"(w6));
      asm volatile("v_permlane32_swap_b32 %0, %1" : "+v"(w5), "+v"(w7));
      bf16x8 pa0 = __builtin_bit_cast(bf16x8, (u32x4){w0, w1, w2, w3});
      bf16x8 pa1 = __builtin_bit_cast(bf16x8, (u32x4){w4, w5, w6, w7});
      const int ph0 = ((kt2*2+0)*2 + hi) ^ l7;
      const int ph1 = ((kt2*2+1)*2 + hi) ^ l7;
      bf16x8 v00 = ld_frag(&Vs[cur][lq*64      + ph0*8]);
      bf16x8 v01 = ld_frag(&Vs[cur][lq*64      + ph1*8]);
      bf16x8 v10 = ld_frag(&Vs[cur][(32+lq)*64 + ph0*8]);
      bf16x8 v11 = ld_frag(&Vs[cur][(32+lq)*64 + ph1*8]);
      __builtin_amdgcn_s_setprio(1);
      o0 = __builtin_amdgcn_mfma_f32_32x32x16_bf16(v00, pa0, o0, 0,0,0);
      o0 = __builtin_amdgcn_mfma_f32_32x32x16_bf16(v01, pa1, o0, 0,0,0);
      o1 = __builtin_amdgcn_mfma_f32_32x32x16_bf16(v10, pa0, o1, 0,0,0);
      o1 = __builtin_amdgcn_mfma_f32_32x32x16_bf16(v11, pa1, o1, 0,0,0);
      lacc = __builtin_amdgcn_mfma_f32_32x32x16_bf16(ones, pa0, lacc, 0,0,0);
      lacc = __builtin_amdgcn_mfma_f32_32x32x16_bf16(ones, pa1, lacc, 0,0,0);
      __builtin_amdgcn_s_setprio(0);
    }

    asm volatile("s_waitcnt vmcnt(0)" ::: "memory");  // next tile landed (hidden under compute)
    __builtin_amdgcn_s_barrier();
  }
  #undef STAGE

  // ---- epilogue: lane-local normalize (l = lacc[0], all D-rows equal) ----
  const float inv = 1.0f / lacc[0];
  size_t base = ((size_t)(b*SEQ + qg))*D_MODEL + h*DK;
  #pragma unroll
  for (int rr=0;rr<4;rr++) {
    u16x4 g0, g1;
    #pragma unroll
    for (int i=0;i<4;i++) { g0[i] = f2bf(o0[rr*4+i]*inv); g1[i] = f2bf(o1[rr*4+i]*inv); }
    *(u16x4*)(AO + base + rr*8 + hi*4)      = g0;
    *(u16x4*)(AO + base + 32 + rr*8 + hi*4) = g1;
  }
}

extern "C" void kernel_launch(void* const* d_in, const int* in_sizes, int n_in,
                              void* d_out, int out_size, void* d_ws, size_t ws_size,
                              hipStream_t stream) {
  const float* x  = (const float*)d_in[0];
  const int*  msk = (const int*)d_in[1];
  const float* wq = (const float*)d_in[2];
  const float* bq = (const float*)d_in[3];
  const float* wk = (const float*)d_in[4];
  const float* bk = (const float*)d_in[5];
  const float* wv = (const float*)d_in[6];
  const float* bv = (const float*)d_in[7];
  const float* wo = (const float*)d_in[8];
  const float* bo = (const float*)d_in[9];
  float* out = (float*)d_out;

  char* ws = (char*)d_ws;
  size_t off = 0;
  u16* Xb   = (u16*)(ws + off); off += (size_t)MTOT*D_MODEL*2;
  u16* Wqkv = (u16*)(ws + off); off += (size_t)3*D_MODEL*D_MODEL*2;
  u16* Wot  = (u16*)(ws + off); off += (size_t)D_MODEL*D_MODEL*2;
  u16* Qb   = (u16*)(ws + off); off += (size_t)BATCH*NHEAD*SEQ*DK*2;
  u16* Kb   = (u16*)(ws + off); off += (size_t)BATCH*NHEAD*SEQ*DK*2;
  u16* Vb   = (u16*)(ws + off); off += (size_t)BATCH*NHEAD*SEQ*DK*2;
  u16* Vtb  = (u16*)(ws + off); off += (size_t)BATCH*NHEAD*SEQ*DK*2;
  u16* AO   = (u16*)(ws + off); off += (size_t)MTOT*D_MODEL*2;
  unsigned long long* Mb = (unsigned long long*)(ws + off);

  k_cvt_x<<<MTOT*D_MODEL/4/256, 256, 0, stream>>>(x, Xb);
  k_wtrans<<<dim3(32,32,4), 256, 0, stream>>>(wq, wk, wv, wo, Wqkv, Wot);
  k_maskpack<<<1024, 256, 0, stream>>>(msk, Mb);
  k_gemm<0><<<(MTOT/128)*(3*D_MODEL/128), 256, 0, stream>>>(
      Xb, Wqkv, MTOT, 3*D_MODEL, D_MODEL, MTOT/128,
      bq, bk, bv, Qb, Kb, Vb, nullptr, nullptr);
  k_vtrans<<<BATCH*NHEAD*(SEQ/64), 256, 0, stream>>>(Vb, Vtb);
  k_attn<<<BATCH*NHEAD*(SEQ/128), 256, 0, stream>>>(Qb, Kb, Vtb, Mb, AO);
  k_gemm<1><<<(MTOT/128)*(D_MODEL/128), 256, 0, stream>>>(
      AO, Wot, MTOT, D_MODEL, D_MODEL, MTOT/128,
      nullptr, nullptr, nullptr, nullptr, nullptr, nullptr, bo, out);
}

// Round 4
// 151.659 us; speedup vs baseline: 1.3155x; 1.3155x over previous
//
#include <hip/hip_runtime.h>
#include <stdint.h>

#define D_MODEL 1024
#define NHEAD   16
#define DK      64
#define BATCH   2
#define SEQ     2048
#define MTOT    (BATCH*SEQ)   // 4096

typedef unsigned short u16;
typedef unsigned int   u32;
typedef u16    u16x4  __attribute__((ext_vector_type(4)));
typedef u16    u16x8  __attribute__((ext_vector_type(8)));
typedef u32    u32x4  __attribute__((ext_vector_type(4)));
typedef __bf16 bf16x8 __attribute__((ext_vector_type(8)));
typedef float  f32x4  __attribute__((ext_vector_type(4)));
typedef float  f32x16 __attribute__((ext_vector_type(16)));

__device__ __forceinline__ u16 f2bf(float f) {
  union { float f; unsigned u; } v; v.f = f;
  return (u16)((v.u + 0x7fffu + ((v.u >> 16) & 1u)) >> 16);
}

__device__ __forceinline__ void gl_lds16(const void* g, void* l) {
  __builtin_amdgcn_global_load_lds((const __attribute__((address_space(1))) void*)g,
                                   (__attribute__((address_space(3))) void*)l, 16, 0, 0);
}

__device__ __forceinline__ bf16x8 ld_frag(const u16* p) {
  return __builtin_bit_cast(bf16x8, *(const u16x8*)p);
}

__device__ __forceinline__ u32 cvtpk(float lo, float hi) {
  u32 r;
  asm("v_cvt_pk_bf16_f32 %0, %1, %2" : "=v"(r) : "v"(lo), "v"(hi));
  return r;
}

// ---------------- prep: x -> bf16 ----------------
__global__ __launch_bounds__(256) void k_cvt_x(const float* __restrict__ x, u16* __restrict__ xb) {
  int i = blockIdx.x * 256 + threadIdx.x;
  const float4 v = ((const float4*)x)[i];
  u16x4 o; o[0]=f2bf(v.x); o[1]=f2bf(v.y); o[2]=f2bf(v.z); o[3]=f2bf(v.w);
  *(u16x4*)(xb + (size_t)i*4) = o;
}

// ---------------- prep: W -> W^T bf16 ----------------
__global__ __launch_bounds__(256) void k_wtrans(const float* __restrict__ wq, const float* __restrict__ wk,
                                                const float* __restrict__ wv, const float* __restrict__ wo,
                                                u16* __restrict__ wqkv_t, u16* __restrict__ wo_t) {
  __shared__ float tile[32][33];
  const int z = blockIdx.z;
  const float* src = (z==0)?wq:(z==1)?wk:(z==2)?wv:wo;
  const int kb = blockIdx.y*32, nb = blockIdx.x*32;
  const int tx = threadIdx.x & 31, ty = threadIdx.x >> 5;  // 32 x 8
  #pragma unroll
  for (int i=0;i<4;i++)
    tile[ty + i*8][tx] = src[(size_t)(kb + ty + i*8)*D_MODEL + nb + tx];
  __syncthreads();
  u16* dst = (z<3) ? (wqkv_t + (size_t)z*D_MODEL*D_MODEL) : wo_t;
  #pragma unroll
  for (int i=0;i<4;i++) {
    int n = nb + ty + i*8, k = kb + tx;
    dst[(size_t)n*D_MODEL + k] = f2bf(tile[tx][ty + i*8]);
  }
}

// ---------------- prep: pack mask to bits ----------------
__global__ __launch_bounds__(256) void k_maskpack(const int* __restrict__ mask,
                                                  unsigned long long* __restrict__ mb) {
  const int wid = blockIdx.x*4 + (threadIdx.x >> 6);   // 0..4095
  const int lane = threadIdx.x & 63;
  for (int t2 = 0; t2 < 32; ++t2) {
    int word = wid*32 + t2;                 // 0..131071
    int row = word >> 5;                    // b*SEQ + i
    int kb = word & 31;
    int m = mask[(size_t)row*SEQ + kb*64 + lane];
    unsigned long long bits = __ballot(m != 0);
    if (lane == 0) mb[word] = bits;
  }
}

// ---------------- prep: V [bh][L][64] -> Vt [bh][64][L] ----------------
__global__ __launch_bounds__(256) void k_vtrans(const u16* __restrict__ V, u16* __restrict__ Vt) {
  __shared__ u16 tile[64][72];
  const int bh = blockIdx.x >> 5;
  const int l0 = (blockIdx.x & 31) * 64;
  const int t = threadIdx.x;
  const u16* src = V + ((size_t)bh*SEQ + l0)*DK;
  #pragma unroll
  for (int j=0;j<2;j++) {
    int idx = t + j*256;                 // 0..511
    int r = idx >> 3, c8 = (idx & 7)*8;
    *(u16x8*)&tile[r][c8] = *(const u16x8*)(src + (size_t)r*DK + c8);
  }
  __syncthreads();
  u16* dst = Vt + (size_t)bh*DK*SEQ + l0;
  #pragma unroll
  for (int j=0;j<2;j++) {
    int idx = t + j*256;
    int d = idx >> 3, k8 = (idx & 7)*8;
    u16x8 o;
    #pragma unroll
    for (int e=0;e<8;e++) o[e] = tile[k8 + e][d];
    *(u16x8*)(dst + (size_t)d*SEQ + k8) = o;
  }
}

// ---------------- 128x128 MFMA GEMM, C = A @ Bt^T (+epilogue) ----------------
template<int EPI>
__global__ __launch_bounds__(256) void k_gemm(const u16* __restrict__ A, const u16* __restrict__ Bt,
                                              const int M, const int N, const int K, const int nbm,
                                              const float* __restrict__ bq, const float* __restrict__ bk,
                                              const float* __restrict__ bv,
                                              u16* __restrict__ Qo, u16* __restrict__ Ko, u16* __restrict__ Vo,
                                              const float* __restrict__ bo, float* __restrict__ out) {
  __shared__ u16 As[128*32];
  __shared__ u16 Bs[128*32];
  const int t = threadIdx.x, lane = t & 63, w = t >> 6;
  const int bm = blockIdx.x % nbm, bn = blockIdx.x / nbm;
  const int brow = bm*128, bcol = bn*128;

  const int srow = w*32 + (lane >> 2);
  const int sswz = (lane & 3) ^ ((lane >> 2) & 3);
  const u16* aS0 = A  + (size_t)(brow + srow)*K + sswz*8;
  const u16* aS1 = aS0 + (size_t)16*K;
  const u16* bS0 = Bt + (size_t)(bcol + srow)*K + sswz*8;
  const u16* bS1 = bS0 + (size_t)16*K;
  u16* aD0 = As + w*1024; u16* aD1 = aD0 + 512;
  u16* bD0 = Bs + w*1024; u16* bD1 = bD0 + 512;

  const int wr = w >> 1, wc = w & 1;
  const int slotA = (lane >> 4) ^ (lane & 3);
  const u16* aRd = As + (wr*64 + (lane & 15))*32 + slotA*8;
  const u16* bRd = Bs + (wc*64 + (lane & 15))*32 + slotA*8;

  f32x4 acc[4][4];
  #pragma unroll
  for (int i=0;i<4;i++)
    #pragma unroll
    for (int j=0;j<4;j++) acc[i][j] = (f32x4){0.f,0.f,0.f,0.f};

  for (int kt = 0; kt < K; kt += 32) {
    gl_lds16(aS0 + kt, aD0);
    gl_lds16(aS1 + kt, aD1);
    gl_lds16(bS0 + kt, bD0);
    gl_lds16(bS1 + kt, bD1);
    __syncthreads();
    bf16x8 af[4], bfr[4];
    #pragma unroll
    for (int m=0;m<4;m++) af[m] = ld_frag(aRd + m*512);
    #pragma unroll
    for (int n=0;n<4;n++) bfr[n] = ld_frag(bRd + n*512);
    #pragma unroll
    for (int m=0;m<4;m++)
      #pragma unroll
      for (int n=0;n<4;n++)
        acc[m][n] = __builtin_amdgcn_mfma_f32_16x16x32_bf16(af[m], bfr[n], acc[m][n], 0,0,0);
    __syncthreads();
  }

  const int orow = brow + wr*64 + (lane >> 4)*4;
  const int ocol = bcol + wc*64 + (lane & 15);
  if (EPI == 0) {
    const int mat = ocol >> 10;
    const float* bias = (mat==0) ? bq : (mat==1) ? bk : bv;
    u16* outp = (mat==0) ? Qo : (mat==1) ? Ko : Vo;
    // fold 1/sqrt(dk) AND log2(e) into Q so attention softmax runs in exp2 domain
    const float scal = (mat==0) ? 0.125f*1.4426950408889634f : 1.0f;
    #pragma unroll
    for (int m=0;m<4;m++) {
      #pragma unroll
      for (int n=0;n<4;n++) {
        int col = ocol + n*16;
        int c = col & 1023;
        float bb = bias[c];
        int h = c >> 6, d = c & 63;
        #pragma unroll
        for (int j=0;j<4;j++) {
          int row = orow + m*16 + j;
          int b = row >> 11, l = row & 2047;
          float v = (acc[m][n][j] + bb) * scal;
          outp[(((size_t)(b*NHEAD + h)*SEQ + l) << 6) + d] = f2bf(v);
        }
      }
    }
  } else {
    #pragma unroll
    for (int m=0;m<4;m++)
      #pragma unroll
      for (int n=0;n<4;n++) {
        int col = ocol + n*16;
        float bb = bo[col];
        #pragma unroll
        for (int j=0;j<4;j++) {
          int row = orow + m*16 + j;
          out[(size_t)row*N + col] = acc[m][n][j] + bb;
        }
      }
  }
}

// ---------------- flash attention: 8-wave KV-split, 32x32 swapped operands ----------------
// Block: 512 thr = 8 waves. Waves 0-3 (half 0): KV tiles 0..15; waves 4-7 (half 1):
// tiles 16..31. Each half stages its own 16KB KV buffer (R2-proven 2-barrier loop).
// Doubles resident waves vs R2 (occupancy 25%->50% cap). Halves merged via LDS epilogue.
__global__ __launch_bounds__(512, 4) void k_attn(const u16* __restrict__ Q, const u16* __restrict__ K,
                                                 const u16* __restrict__ Vt,
                                                 const unsigned long long* __restrict__ MB,
                                                 u16* __restrict__ AO) {
  __shared__ char smem[36864];   // staging: 2 halves x (K 8KB + V 8KB) = 32KB; merge: 35KB
  const int t = threadIdx.x, lane = t & 63, w = t >> 6;
  const int hf = w >> 2, widx = w & 3;
  // XCD-aware bijective swizzle: 512 blocks = 8 XCD x 64
  const int bid = blockIdx.x;
  const int swz = (bid & 7)*64 + (bid >> 3);
  const int bh = swz >> 4;
  const int q0 = (swz & 15) * 128;
  const int b = bh >> 4, h = bh & 15;
  const int lq = lane & 31, hi = lane >> 5, l7 = lane & 7;

  u16* Kbuf = (u16*)(smem + hf*16384);
  u16* Vbuf = (u16*)(smem + hf*16384 + 8192);

  const int qg = q0 + widx*32 + lq;
  const u16* qp = Q + ((size_t)bh*SEQ + qg)*DK + hi*8;
  bf16x8 qf[4];
  #pragma unroll
  for (int ks=0;ks<4;ks++) qf[ks] = ld_frag(qp + ks*16);

  // staging: within a half, wave widx stages rows widx*16..+15 of the 64-key tile
  const int srow = widx*16 + (lane >> 3);
  const int sswz = l7 ^ ((lane >> 3) & 7);        // pre-swizzled global source
  const u16* kSb = K  + ((size_t)bh*SEQ + srow)*DK + sswz*8;
  const u16* vSb = Vt + ((size_t)bh*DK + srow)*SEQ + sswz*8;
  u16* kD0 = Kbuf + widx*1024; u16* kD1 = kD0 + 512;
  u16* vD0 = Vbuf + widx*1024; u16* vD1 = vD0 + 512;

  f32x16 o0 = 0.f, o1 = 0.f;
  float m_run = -1e30f, l_run = 0.f;
  const unsigned long long* mbp = MB + ((size_t)b*SEQ + qg)*32;

  for (int i = 0; i < 16; ++i) {
    const int ktg = hf*16 + i;
    const u16* kp = kSb + (size_t)ktg*64*DK;
    const u16* vp = vSb + ktg*64;
    gl_lds16(kp, kD0); gl_lds16(kp + 8*DK, kD1);
    gl_lds16(vp, vD0); gl_lds16(vp + 8*SEQ, vD1);
    __syncthreads();

    // ---- S^T: 2 key-subtiles of 32 ----
    f32x16 s0 = 0.f, s1 = 0.f;
    #pragma unroll
    for (int ks=0;ks<4;ks++) {
      const int ph = (ks*2 + hi) ^ l7;
      bf16x8 kf0 = ld_frag(Kbuf + lq*64 + ph*8);
      bf16x8 kf1 = ld_frag(Kbuf + (32+lq)*64 + ph*8);
      s0 = __builtin_amdgcn_mfma_f32_32x32x16_bf16(kf0, qf[ks], s0, 0,0,0);
      s1 = __builtin_amdgcn_mfma_f32_32x32x16_bf16(kf1, qf[ks], s1, 0,0,0);
    }

    unsigned long long mb = mbp[ktg];
    if (!__all(mb == ~0ull)) {
      #pragma unroll
      for (int r=0;r<16;r++) {
        int kl = (r&3) + 8*(r>>2) + 4*hi;
        if (!((mb >> kl) & 1ull)) s0[r] = -1e9f;
        if (!((mb >> (kl+32)) & 1ull)) s1[r] = -1e9f;
      }
    }

    // ---- online softmax: tree max, defer-max (THR=8, exp2 domain) ----
    float tm[16];
    #pragma unroll
    for (int r=0;r<16;r++) tm[r] = fmaxf(s0[r], s1[r]);
    #pragma unroll
    for (int st=8; st>0; st>>=1)
      #pragma unroll
      for (int r=0;r<8;r++) if (r < st) tm[r] = fmaxf(tm[r], tm[r+st]);
    float mx = fmaxf(tm[0], __shfl_xor(tm[0], 32));
    if (!__all(mx <= m_run + 8.0f)) {
      float m_new = fmaxf(m_run, mx);
      float corr = __builtin_amdgcn_exp2f(m_run - m_new);
      l_run *= corr;
      #pragma unroll
      for (int r=0;r<16;r++) { o0[r] *= corr; o1[r] *= corr; }
      m_run = m_new;
    }
    float ts[16];
    #pragma unroll
    for (int r=0;r<16;r++) {
      s0[r] = __builtin_amdgcn_exp2f(s0[r] - m_run);
      s1[r] = __builtin_amdgcn_exp2f(s1[r] - m_run);
      ts[r] = s0[r] + s1[r];
    }
    #pragma unroll
    for (int st=8; st>0; st>>=1)
      #pragma unroll
      for (int r=0;r<8;r++) if (r < st) ts[r] += ts[r+st];
    l_run += ts[0] + __shfl_xor(ts[0], 32);

    // ---- P -> bf16 PA frags (cvt_pk + permlane32_swap); PV ----
    #pragma unroll
    for (int kt2=0;kt2<2;kt2++) {
      const f32x16& sv = kt2 ? s1 : s0;
      u32 w0 = cvtpk(sv[0],  sv[1]),  w1 = cvtpk(sv[2],  sv[3]);
      u32 w2 = cvtpk(sv[4],  sv[5]),  w3 = cvtpk(sv[6],  sv[7]);
      u32 w4 = cvtpk(sv[8],  sv[9]),  w5 = cvtpk(sv[10], sv[11]);
      u32 w6 = cvtpk(sv[12], sv[13]), w7 = cvtpk(sv[14], sv[15]);
      asm volatile("v_permlane32_swap_b32 %0, %1" : "+v"(w0), "+v"(w2));
      asm volatile("v_permlane32_swap_b32 %0, %1" : "+v"(w1), "+v"(w3));
      asm volatile("v_permlane32_swap_b32 %0, %1" : "+v"(w4), "+v"(w6));
      asm volatile("v_permlane32_swap_b32 %0, %1" : "+v"(w5), "+v"(w7));
      bf16x8 pa0 = __builtin_bit_cast(bf16x8, (u32x4){w0, w1, w2, w3});
      bf16x8 pa1 = __builtin_bit_cast(bf16x8, (u32x4){w4, w5, w6, w7});
      const int ph0 = ((kt2*2+0)*2 + hi) ^ l7;
      const int ph1 = ((kt2*2+1)*2 + hi) ^ l7;
      bf16x8 v00 = ld_frag(Vbuf + lq*64      + ph0*8);
      bf16x8 v01 = ld_frag(Vbuf + lq*64      + ph1*8);
      bf16x8 v10 = ld_frag(Vbuf + (32+lq)*64 + ph0*8);
      bf16x8 v11 = ld_frag(Vbuf + (32+lq)*64 + ph1*8);
      o0 = __builtin_amdgcn_mfma_f32_32x32x16_bf16(v00, pa0, o0, 0,0,0);
      o0 = __builtin_amdgcn_mfma_f32_32x32x16_bf16(v01, pa1, o0, 0,0,0);
      o1 = __builtin_amdgcn_mfma_f32_32x32x16_bf16(v10, pa0, o1, 0,0,0);
      o1 = __builtin_amdgcn_mfma_f32_32x32x16_bf16(v11, pa1, o1, 0,0,0);
    }
    __syncthreads();
  }

  // ---- merge halves via LDS (stride-35 f32 slots: conflict-free) ----
  float* marea = (float*)smem;
  if (hf == 1) {
    float* p = marea + (size_t)(widx*64 + lane)*35;
    #pragma unroll
    for (int r=0;r<16;r++) { p[r] = o0[r]; p[16+r] = o1[r]; }
    p[32] = m_run; p[33] = l_run;
  }
  __syncthreads();
  if (hf == 0) {
    const float* p = marea + (size_t)(widx*64 + lane)*35;
    float m1 = p[32], l1 = p[33];
    float mm = fmaxf(m_run, m1);
    float c0 = __builtin_amdgcn_exp2f(m_run - mm);
    float c1 = __builtin_amdgcn_exp2f(m1 - mm);
    float inv = 1.0f / (l_run*c0 + l1*c1);
    size_t base = ((size_t)(b*SEQ + qg))*D_MODEL + h*DK;
    u16x4 g;
    #pragma unroll
    for (int rr=0;rr<4;rr++) {
      #pragma unroll
      for (int i2=0;i2<4;i2++) g[i2] = f2bf((o0[rr*4+i2]*c0 + p[rr*4+i2]*c1) * inv);
      *(u16x4*)(AO + base + rr*8 + hi*4) = g;
    }
    #pragma unroll
    for (int rr=0;rr<4;rr++) {
      #pragma unroll
      for (int i2=0;i2<4;i2++) g[i2] = f2bf((o1[rr*4+i2]*c0 + p[16+rr*4+i2]*c1) * inv);
      *(u16x4*)(AO + base + 32 + rr*8 + hi*4) = g;
    }
  }
}

extern "C" void kernel_launch(void* const* d_in, const int* in_sizes, int n_in,
                              void* d_out, int out_size, void* d_ws, size_t ws_size,
                              hipStream_t stream) {
  const float* x  = (const float*)d_in[0];
  const int*  msk = (const int*)d_in[1];
  const float* wq = (const float*)d_in[2];
  const float* bq = (const float*)d_in[3];
  const float* wk = (const float*)d_in[4];
  const float* bk = (const float*)d_in[5];
  const float* wv = (const float*)d_in[6];
  const float* bv = (const float*)d_in[7];
  const float* wo = (const float*)d_in[8];
  const float* bo = (const float*)d_in[9];
  float* out = (float*)d_out;

  char* ws = (char*)d_ws;
  size_t off = 0;
  u16* Xb   = (u16*)(ws + off); off += (size_t)MTOT*D_MODEL*2;
  u16* Wqkv = (u16*)(ws + off); off += (size_t)3*D_MODEL*D_MODEL*2;
  u16* Wot  = (u16*)(ws + off); off += (size_t)D_MODEL*D_MODEL*2;
  u16* Qb   = (u16*)(ws + off); off += (size_t)BATCH*NHEAD*SEQ*DK*2;
  u16* Kb   = (u16*)(ws + off); off += (size_t)BATCH*NHEAD*SEQ*DK*2;
  u16* Vb   = (u16*)(ws + off); off += (size_t)BATCH*NHEAD*SEQ*DK*2;
  u16* Vtb  = (u16*)(ws + off); off += (size_t)BATCH*NHEAD*SEQ*DK*2;
  u16* AO   = (u16*)(ws + off); off += (size_t)MTOT*D_MODEL*2;
  unsigned long long* Mb = (unsigned long long*)(ws + off);

  k_cvt_x<<<MTOT*D_MODEL/4/256, 256, 0, stream>>>(x, Xb);
  k_wtrans<<<dim3(32,32,4), 256, 0, stream>>>(wq, wk, wv, wo, Wqkv, Wot);
  k_maskpack<<<1024, 256, 0, stream>>>(msk, Mb);
  k_gemm<0><<<(MTOT/128)*(3*D_MODEL/128), 256, 0, stream>>>(
      Xb, Wqkv, MTOT, 3*D_MODEL, D_MODEL, MTOT/128,
      bq, bk, bv, Qb, Kb, Vb, nullptr, nullptr);
  k_vtrans<<<BATCH*NHEAD*(SEQ/64), 256, 0, stream>>>(Vb, Vtb);
  k_attn<<<BATCH*NHEAD*(SEQ/128), 512, 0, stream>>>(Qb, Kb, Vtb, Mb, AO);
  k_gemm<1><<<(MTOT/128)*(D_MODEL/128), 256, 0, stream>>>(
      AO, Wot, MTOT, D_MODEL, D_MODEL, MTOT/128,
      nullptr, nullptr, nullptr, nullptr, nullptr, nullptr, bo, out);
}

// Round 5
// 150.516 us; speedup vs baseline: 1.3255x; 1.0076x over previous
//
#include <hip/hip_runtime.h>
#include <stdint.h>

#define D_MODEL 1024
#define NHEAD   16
#define DK      64
#define BATCH   2
#define SEQ     2048
#define MTOT    (BATCH*SEQ)   // 4096

typedef unsigned short u16;
typedef unsigned int   u32;
typedef u16    u16x4  __attribute__((ext_vector_type(4)));
typedef u16    u16x8  __attribute__((ext_vector_type(8)));
typedef u32    u32x4  __attribute__((ext_vector_type(4)));
typedef __bf16 bf16x8 __attribute__((ext_vector_type(8)));
typedef float  f32x4  __attribute__((ext_vector_type(4)));
typedef float  f32x16 __attribute__((ext_vector_type(16)));

__device__ __forceinline__ u16 f2bf(float f) {
  union { float f; unsigned u; } v; v.f = f;
  return (u16)((v.u + 0x7fffu + ((v.u >> 16) & 1u)) >> 16);
}

__device__ __forceinline__ void gl_lds16(const void* g, void* l) {
  __builtin_amdgcn_global_load_lds((const __attribute__((address_space(1))) void*)g,
                                   (__attribute__((address_space(3))) void*)l, 16, 0, 0);
}

__device__ __forceinline__ bf16x8 ld_frag(const u16* p) {
  return __builtin_bit_cast(bf16x8, *(const u16x8*)p);
}

__device__ __forceinline__ u32 cvtpk(float lo, float hi) {
  u32 r;
  asm("v_cvt_pk_bf16_f32 %0, %1, %2" : "=v"(r) : "v"(lo), "v"(hi));
  return r;
}

// ---------------- prep: x -> bf16 ----------------
__global__ __launch_bounds__(256) void k_cvt_x(const float* __restrict__ x, u16* __restrict__ xb) {
  int i = blockIdx.x * 256 + threadIdx.x;
  const float4 v = ((const float4*)x)[i];
  u16x4 o; o[0]=f2bf(v.x); o[1]=f2bf(v.y); o[2]=f2bf(v.z); o[3]=f2bf(v.w);
  *(u16x4*)(xb + (size_t)i*4) = o;
}

// ---------------- prep: W -> W^T bf16 ----------------
__global__ __launch_bounds__(256) void k_wtrans(const float* __restrict__ wq, const float* __restrict__ wk,
                                                const float* __restrict__ wv, const float* __restrict__ wo,
                                                u16* __restrict__ wqkv_t, u16* __restrict__ wo_t) {
  __shared__ float tile[32][33];
  const int z = blockIdx.z;
  const float* src = (z==0)?wq:(z==1)?wk:(z==2)?wv:wo;
  const int kb = blockIdx.y*32, nb = blockIdx.x*32;
  const int tx = threadIdx.x & 31, ty = threadIdx.x >> 5;  // 32 x 8
  #pragma unroll
  for (int i=0;i<4;i++)
    tile[ty + i*8][tx] = src[(size_t)(kb + ty + i*8)*D_MODEL + nb + tx];
  __syncthreads();
  u16* dst = (z<3) ? (wqkv_t + (size_t)z*D_MODEL*D_MODEL) : wo_t;
  #pragma unroll
  for (int i=0;i<4;i++) {
    int n = nb + ty + i*8, k = kb + tx;
    dst[(size_t)n*D_MODEL + k] = f2bf(tile[tx][ty + i*8]);
  }
}

// ---------------- prep: pack mask to bits ----------------
__global__ __launch_bounds__(256) void k_maskpack(const int* __restrict__ mask,
                                                  unsigned long long* __restrict__ mb) {
  const int wid = blockIdx.x*4 + (threadIdx.x >> 6);   // 0..4095
  const int lane = threadIdx.x & 63;
  for (int t2 = 0; t2 < 32; ++t2) {
    int word = wid*32 + t2;                 // 0..131071
    int row = word >> 5;                    // b*SEQ + i
    int kb = word & 31;
    int m = mask[(size_t)row*SEQ + kb*64 + lane];
    unsigned long long bits = __ballot(m != 0);
    if (lane == 0) mb[word] = bits;
  }
}

// ---------------- prep: V [bh][L][64] -> Vt [bh][64][L] ----------------
__global__ __launch_bounds__(256) void k_vtrans(const u16* __restrict__ V, u16* __restrict__ Vt) {
  __shared__ u16 tile[64][72];
  const int bh = blockIdx.x >> 5;
  const int l0 = (blockIdx.x & 31) * 64;
  const int t = threadIdx.x;
  const u16* src = V + ((size_t)bh*SEQ + l0)*DK;
  #pragma unroll
  for (int j=0;j<2;j++) {
    int idx = t + j*256;                 // 0..511
    int r = idx >> 3, c8 = (idx & 7)*8;
    *(u16x8*)&tile[r][c8] = *(const u16x8*)(src + (size_t)r*DK + c8);
  }
  __syncthreads();
  u16* dst = Vt + (size_t)bh*DK*SEQ + l0;
  #pragma unroll
  for (int j=0;j<2;j++) {
    int idx = t + j*256;
    int d = idx >> 3, k8 = (idx & 7)*8;
    u16x8 o;
    #pragma unroll
    for (int e=0;e<8;e++) o[e] = tile[k8 + e][d];
    *(u16x8*)(dst + (size_t)d*SEQ + k8) = o;
  }
}

// ---------------- 128x128 MFMA GEMM, C = A @ Bt^T (+epilogue) ----------------
template<int EPI>
__global__ __launch_bounds__(256) void k_gemm(const u16* __restrict__ A, const u16* __restrict__ Bt,
                                              const int M, const int N, const int K, const int nbm,
                                              const float* __restrict__ bq, const float* __restrict__ bk,
                                              const float* __restrict__ bv,
                                              u16* __restrict__ Qo, u16* __restrict__ Ko, u16* __restrict__ Vo,
                                              const float* __restrict__ bo, float* __restrict__ out) {
  __shared__ u16 As[128*32];
  __shared__ u16 Bs[128*32];
  const int t = threadIdx.x, lane = t & 63, w = t >> 6;
  const int bm = blockIdx.x % nbm, bn = blockIdx.x / nbm;
  const int brow = bm*128, bcol = bn*128;

  const int srow = w*32 + (lane >> 2);
  const int sswz = (lane & 3) ^ ((lane >> 2) & 3);
  const u16* aS0 = A  + (size_t)(brow + srow)*K + sswz*8;
  const u16* aS1 = aS0 + (size_t)16*K;
  const u16* bS0 = Bt + (size_t)(bcol + srow)*K + sswz*8;
  const u16* bS1 = bS0 + (size_t)16*K;
  u16* aD0 = As + w*1024; u16* aD1 = aD0 + 512;
  u16* bD0 = Bs + w*1024; u16* bD1 = bD0 + 512;

  const int wr = w >> 1, wc = w & 1;
  const int slotA = (lane >> 4) ^ (lane & 3);
  const u16* aRd = As + (wr*64 + (lane & 15))*32 + slotA*8;
  const u16* bRd = Bs + (wc*64 + (lane & 15))*32 + slotA*8;

  f32x4 acc[4][4];
  #pragma unroll
  for (int i=0;i<4;i++)
    #pragma unroll
    for (int j=0;j<4;j++) acc[i][j] = (f32x4){0.f,0.f,0.f,0.f};

  for (int kt = 0; kt < K; kt += 32) {
    gl_lds16(aS0 + kt, aD0);
    gl_lds16(aS1 + kt, aD1);
    gl_lds16(bS0 + kt, bD0);
    gl_lds16(bS1 + kt, bD1);
    __syncthreads();
    bf16x8 af[4], bfr[4];
    #pragma unroll
    for (int m=0;m<4;m++) af[m] = ld_frag(aRd + m*512);
    #pragma unroll
    for (int n=0;n<4;n++) bfr[n] = ld_frag(bRd + n*512);
    #pragma unroll
    for (int m=0;m<4;m++)
      #pragma unroll
      for (int n=0;n<4;n++)
        acc[m][n] = __builtin_amdgcn_mfma_f32_16x16x32_bf16(af[m], bfr[n], acc[m][n], 0,0,0);
    __syncthreads();
  }

  const int orow = brow + wr*64 + (lane >> 4)*4;
  const int ocol = bcol + wc*64 + (lane & 15);
  if (EPI == 0) {
    const int mat = ocol >> 10;
    const float* bias = (mat==0) ? bq : (mat==1) ? bk : bv;
    u16* outp = (mat==0) ? Qo : (mat==1) ? Ko : Vo;
    // fold 1/sqrt(dk) AND log2(e) into Q so attention softmax runs in exp2 domain
    const float scal = (mat==0) ? 0.125f*1.4426950408889634f : 1.0f;
    #pragma unroll
    for (int m=0;m<4;m++) {
      #pragma unroll
      for (int n=0;n<4;n++) {
        int col = ocol + n*16;
        int c = col & 1023;
        float bb = bias[c];
        int h = c >> 6, d = c & 63;
        #pragma unroll
        for (int j=0;j<4;j++) {
          int row = orow + m*16 + j;
          int b = row >> 11, l = row & 2047;
          float v = (acc[m][n][j] + bb) * scal;
          outp[(((size_t)(b*NHEAD + h)*SEQ + l) << 6) + d] = f2bf(v);
        }
      }
    }
  } else {
    #pragma unroll
    for (int m=0;m<4;m++)
      #pragma unroll
      for (int n=0;n<4;n++) {
        int col = ocol + n*16;
        float bb = bo[col];
        #pragma unroll
        for (int j=0;j<4;j++) {
          int row = orow + m*16 + j;
          out[(size_t)row*N + col] = acc[m][n][j] + bb;
        }
      }
  }
}

// ---------------- flash attention: 8-wave KV-split, 32-key softmax subtiles, KV dbuf ----
// Block: 512 thr = 8 waves. Half hf=w>>2 owns KV tiles [hf*16, hf*16+16).
// Per 64-key tile: two sequential 32-key subtiles (one f32x16 S live at a time ->
// fits the 128-reg unified budget at 4 waves/SIMD, no scratch spill).
// 2-phase pipeline: STAGE(next) issued before compute; vmcnt(0)+barrier after.
__global__ __launch_bounds__(512, 4) void k_attn(const u16* __restrict__ Q, const u16* __restrict__ K,
                                                 const u16* __restrict__ Vt,
                                                 const unsigned long long* __restrict__ MB,
                                                 u16* __restrict__ AO) {
  __shared__ char smem[65536];   // 2 bufs x 2 halves x (K 8KB + V 8KB); merge reuses
  const int t = threadIdx.x, lane = t & 63, w = t >> 6;
  const int hf = w >> 2, widx = w & 3;
  // XCD-aware bijective swizzle: 512 blocks = 8 XCD x 64
  const int bid = blockIdx.x;
  const int swz = (bid & 7)*64 + (bid >> 3);
  const int bh = swz >> 4;
  const int q0 = (swz & 15) * 128;
  const int b = bh >> 4, h = bh & 15;
  const int lq = lane & 31, hi = lane >> 5, l7 = lane & 7;

  const int qg = q0 + widx*32 + lq;
  const u16* qp = Q + ((size_t)bh*SEQ + qg)*DK + hi*8;
  bf16x8 qf[4];
  #pragma unroll
  for (int ks=0;ks<4;ks++) qf[ks] = ld_frag(qp + ks*16);

  // staging: within a half, wave widx stages rows widx*16..+15 of the 64-key tile
  const int srow = widx*16 + (lane >> 3);
  const int sswz = l7 ^ ((lane >> 3) & 7);        // pre-swizzled global source
  const u16* kSb = K  + ((size_t)bh*SEQ + srow)*DK + sswz*8;
  const u16* vSb = Vt + ((size_t)bh*DK + srow)*SEQ + sswz*8;

  f32x16 o0 = 0.f, o1 = 0.f;
  float m_run = -1e30f, l_run = 0.f;
  const unsigned long long* mbp = MB + ((size_t)b*SEQ + qg)*32;

  #define STAGE(buf, tile) do {                                           \
    const u16* kp_ = kSb + (size_t)(tile)*64*DK;                          \
    const u16* vp_ = vSb + (size_t)(tile)*64;                             \
    u16* kd_ = (u16*)(smem + (buf)*32768 + hf*16384) + widx*1024;         \
    u16* vd_ = (u16*)(smem + (buf)*32768 + hf*16384 + 8192) + widx*1024;  \
    gl_lds16(kp_, kd_); gl_lds16(kp_ + 8*DK, kd_ + 512);                  \
    gl_lds16(vp_, vd_); gl_lds16(vp_ + 8*SEQ, vd_ + 512);                 \
  } while (0)

  STAGE(0, hf*16);
  asm volatile("s_waitcnt vmcnt(0)" ::: "memory");
  __builtin_amdgcn_s_barrier();

  for (int i = 0; i < 16; ++i) {
    const int cur = i & 1;
    if (i + 1 < 16) STAGE(cur ^ 1, hf*16 + i + 1);   // in flight across compute
    const u16* Kbuf = (const u16*)(smem + cur*32768 + hf*16384);
    const u16* Vbuf = (const u16*)(smem + cur*32768 + hf*16384 + 8192);
    const unsigned long long mb = mbp[hf*16 + i];
    const bool full = __all(mb == ~0ull);

    #pragma unroll
    for (int sub = 0; sub < 2; ++sub) {
      // ---- S^T for 32 keys ----
      f32x16 s = 0.f;
      __builtin_amdgcn_s_setprio(1);
      #pragma unroll
      for (int ks=0;ks<4;ks++) {
        const int ph = (ks*2 + hi) ^ l7;
        bf16x8 kf = ld_frag(Kbuf + (sub*32 + lq)*64 + ph*8);
        s = __builtin_amdgcn_mfma_f32_32x32x16_bf16(kf, qf[ks], s, 0,0,0);
      }
      __builtin_amdgcn_s_setprio(0);

      if (!full) {
        #pragma unroll
        for (int r=0;r<16;r++) {
          int kl = sub*32 + (r&3) + 8*(r>>2) + 4*hi;
          if (!((mb >> kl) & 1ull)) s[r] = -1e9f;
        }
      }

      // ---- online softmax (tree reduce), defer-max THR=8 (exp2 domain) ----
      float tm[8];
      #pragma unroll
      for (int r=0;r<8;r++) tm[r] = fmaxf(s[r], s[8+r]);
      #pragma unroll
      for (int st=4; st>0; st>>=1)
        #pragma unroll
        for (int r=0;r<4;r++) if (r < st) tm[r] = fmaxf(tm[r], tm[r+st]);
      float mx = fmaxf(tm[0], __shfl_xor(tm[0], 32));
      if (!__all(mx <= m_run + 8.0f)) {
        float m_new = fmaxf(m_run, mx);
        float corr = __builtin_amdgcn_exp2f(m_run - m_new);
        l_run *= corr;
        #pragma unroll
        for (int r=0;r<16;r++) { o0[r] *= corr; o1[r] *= corr; }
        m_run = m_new;
      }
      #pragma unroll
      for (int r=0;r<16;r++) s[r] = __builtin_amdgcn_exp2f(s[r] - m_run);
      float ts[8];
      #pragma unroll
      for (int r=0;r<8;r++) ts[r] = s[r] + s[8+r];
      #pragma unroll
      for (int st=4; st>0; st>>=1)
        #pragma unroll
        for (int r=0;r<4;r++) if (r < st) ts[r] += ts[r+st];
      l_run += ts[0] + __shfl_xor(ts[0], 32);

      // ---- P -> bf16 PA frags (cvt_pk + permlane32_swap); PV ----
      u32 w0 = cvtpk(s[0],  s[1]),  w1 = cvtpk(s[2],  s[3]);
      u32 w2 = cvtpk(s[4],  s[5]),  w3 = cvtpk(s[6],  s[7]);
      u32 w4 = cvtpk(s[8],  s[9]),  w5 = cvtpk(s[10], s[11]);
      u32 w6 = cvtpk(s[12], s[13]), w7 = cvtpk(s[14], s[15]);
      asm volatile("v_permlane32_swap_b32 %0, %1" : "+v"(w0), "+v"(w2));
      asm volatile("v_permlane32_swap_b32 %0, %1" : "+v"(w1), "+v"(w3));
      asm volatile("v_permlane32_swap_b32 %0, %1" : "+v"(w4), "+v"(w6));
      asm volatile("v_permlane32_swap_b32 %0, %1" : "+v"(w5), "+v"(w7));
      bf16x8 pa0 = __builtin_bit_cast(bf16x8, (u32x4){w0, w1, w2, w3});
      bf16x8 pa1 = __builtin_bit_cast(bf16x8, (u32x4){w4, w5, w6, w7});
      const int ph0 = ((sub*2+0)*2 + hi) ^ l7;
      const int ph1 = ((sub*2+1)*2 + hi) ^ l7;
      bf16x8 v00 = ld_frag(Vbuf + lq*64      + ph0*8);
      bf16x8 v01 = ld_frag(Vbuf + lq*64      + ph1*8);
      bf16x8 v10 = ld_frag(Vbuf + (32+lq)*64 + ph0*8);
      bf16x8 v11 = ld_frag(Vbuf + (32+lq)*64 + ph1*8);
      __builtin_amdgcn_s_setprio(1);
      o0 = __builtin_amdgcn_mfma_f32_32x32x16_bf16(v00, pa0, o0, 0,0,0);
      o0 = __builtin_amdgcn_mfma_f32_32x32x16_bf16(v01, pa1, o0, 0,0,0);
      o1 = __builtin_amdgcn_mfma_f32_32x32x16_bf16(v10, pa0, o1, 0,0,0);
      o1 = __builtin_amdgcn_mfma_f32_32x32x16_bf16(v11, pa1, o1, 0,0,0);
      __builtin_amdgcn_s_setprio(0);
    }

    asm volatile("s_waitcnt vmcnt(0)" ::: "memory");  // next tile landed (hidden under compute)
    __builtin_amdgcn_s_barrier();
  }
  #undef STAGE

  // ---- merge halves via LDS (stride-35 f32 slots: conflict-free) ----
  float* marea = (float*)smem;
  if (hf == 1) {
    float* p = marea + (size_t)(widx*64 + lane)*35;
    #pragma unroll
    for (int r=0;r<16;r++) { p[r] = o0[r]; p[16+r] = o1[r]; }
    p[32] = m_run; p[33] = l_run;
  }
  __syncthreads();
  if (hf == 0) {
    const float* p = marea + (size_t)(widx*64 + lane)*35;
    float m1 = p[32], l1 = p[33];
    float mm = fmaxf(m_run, m1);
    float c0 = __builtin_amdgcn_exp2f(m_run - mm);
    float c1 = __builtin_amdgcn_exp2f(m1 - mm);
    float inv = 1.0f / (l_run*c0 + l1*c1);
    size_t base = ((size_t)(b*SEQ + qg))*D_MODEL + h*DK;
    u16x4 g;
    #pragma unroll
    for (int rr=0;rr<4;rr++) {
      #pragma unroll
      for (int i2=0;i2<4;i2++) g[i2] = f2bf((o0[rr*4+i2]*c0 + p[rr*4+i2]*c1) * inv);
      *(u16x4*)(AO + base + rr*8 + hi*4) = g;
    }
    #pragma unroll
    for (int rr=0;rr<4;rr++) {
      #pragma unroll
      for (int i2=0;i2<4;i2++) g[i2] = f2bf((o1[rr*4+i2]*c0 + p[16+rr*4+i2]*c1) * inv);
      *(u16x4*)(AO + base + 32 + rr*8 + hi*4) = g;
    }
  }
}

extern "C" void kernel_launch(void* const* d_in, const int* in_sizes, int n_in,
                              void* d_out, int out_size, void* d_ws, size_t ws_size,
                              hipStream_t stream) {
  const float* x  = (const float*)d_in[0];
  const int*  msk = (const int*)d_in[1];
  const float* wq = (const float*)d_in[2];
  const float* bq = (const float*)d_in[3];
  const float* wk = (const float*)d_in[4];
  const float* bk = (const float*)d_in[5];
  const float* wv = (const float*)d_in[6];
  const float* bv = (const float*)d_in[7];
  const float* wo = (const float*)d_in[8];
  const float* bo = (const float*)d_in[9];
  float* out = (float*)d_out;

  char* ws = (char*)d_ws;
  size_t off = 0;
  u16* Xb   = (u16*)(ws + off); off += (size_t)MTOT*D_MODEL*2;
  u16* Wqkv = (u16*)(ws + off); off += (size_t)3*D_MODEL*D_MODEL*2;
  u16* Wot  = (u16*)(ws + off); off += (size_t)D_MODEL*D_MODEL*2;
  u16* Qb   = (u16*)(ws + off); off += (size_t)BATCH*NHEAD*SEQ*DK*2;
  u16* Kb   = (u16*)(ws + off); off += (size_t)BATCH*NHEAD*SEQ*DK*2;
  u16* Vb   = (u16*)(ws + off); off += (size_t)BATCH*NHEAD*SEQ*DK*2;
  u16* Vtb  = (u16*)(ws + off); off += (size_t)BATCH*NHEAD*SEQ*DK*2;
  u16* AO   = (u16*)(ws + off); off += (size_t)MTOT*D_MODEL*2;
  unsigned long long* Mb = (unsigned long long*)(ws + off);

  k_cvt_x<<<MTOT*D_MODEL/4/256, 256, 0, stream>>>(x, Xb);
  k_wtrans<<<dim3(32,32,4), 256, 0, stream>>>(wq, wk, wv, wo, Wqkv, Wot);
  k_maskpack<<<1024, 256, 0, stream>>>(msk, Mb);
  k_gemm<0><<<(MTOT/128)*(3*D_MODEL/128), 256, 0, stream>>>(
      Xb, Wqkv, MTOT, 3*D_MODEL, D_MODEL, MTOT/128,
      bq, bk, bv, Qb, Kb, Vb, nullptr, nullptr);
  k_vtrans<<<BATCH*NHEAD*(SEQ/64), 256, 0, stream>>>(Vb, Vtb);
  k_attn<<<BATCH*NHEAD*(SEQ/128), 512, 0, stream>>>(Qb, Kb, Vtb, Mb, AO);
  k_gemm<1><<<(MTOT/128)*(D_MODEL/128), 256, 0, stream>>>(
      AO, Wot, MTOT, D_MODEL, D_MODEL, MTOT/128,
      nullptr, nullptr, nullptr, nullptr, nullptr, nullptr, bo, out);
}

// Round 6
// 148.808 us; speedup vs baseline: 1.3407x; 1.0115x over previous
//
#include <hip/hip_runtime.h>
#include <stdint.h>

#define D_MODEL 1024
#define NHEAD   16
#define DK      64
#define BATCH   2
#define SEQ     2048
#define MTOT    (BATCH*SEQ)   // 4096

typedef unsigned short u16;
typedef unsigned int   u32;
typedef u16    u16x4  __attribute__((ext_vector_type(4)));
typedef u16    u16x8  __attribute__((ext_vector_type(8)));
typedef u32    u32x4  __attribute__((ext_vector_type(4)));
typedef __bf16 bf16x8 __attribute__((ext_vector_type(8)));
typedef float  f32x4  __attribute__((ext_vector_type(4)));
typedef float  f32x16 __attribute__((ext_vector_type(16)));

__device__ __forceinline__ u16 f2bf(float f) {
  union { float f; unsigned u; } v; v.f = f;
  return (u16)((v.u + 0x7fffu + ((v.u >> 16) & 1u)) >> 16);
}

__device__ __forceinline__ void gl_lds16(const void* g, void* l) {
  __builtin_amdgcn_global_load_lds((const __attribute__((address_space(1))) void*)g,
                                   (__attribute__((address_space(3))) void*)l, 16, 0, 0);
}

__device__ __forceinline__ bf16x8 ld_frag(const u16* p) {
  return __builtin_bit_cast(bf16x8, *(const u16x8*)p);
}

__device__ __forceinline__ u32 cvtpk(float lo, float hi) {
  u32 r;
  asm("v_cvt_pk_bf16_f32 %0, %1, %2" : "=v"(r) : "v"(lo), "v"(hi));
  return r;
}

// ---------------- prep: x -> bf16 ----------------
__global__ __launch_bounds__(256) void k_cvt_x(const float* __restrict__ x, u16* __restrict__ xb) {
  int i = blockIdx.x * 256 + threadIdx.x;
  const float4 v = ((const float4*)x)[i];
  u16x4 o; o[0]=f2bf(v.x); o[1]=f2bf(v.y); o[2]=f2bf(v.z); o[3]=f2bf(v.w);
  *(u16x4*)(xb + (size_t)i*4) = o;
}

// ---------------- prep: W -> W^T bf16 ----------------
__global__ __launch_bounds__(256) void k_wtrans(const float* __restrict__ wq, const float* __restrict__ wk,
                                                const float* __restrict__ wv, const float* __restrict__ wo,
                                                u16* __restrict__ wqkv_t, u16* __restrict__ wo_t) {
  __shared__ float tile[32][33];
  const int z = blockIdx.z;
  const float* src = (z==0)?wq:(z==1)?wk:(z==2)?wv:wo;
  const int kb = blockIdx.y*32, nb = blockIdx.x*32;
  const int tx = threadIdx.x & 31, ty = threadIdx.x >> 5;  // 32 x 8
  #pragma unroll
  for (int i=0;i<4;i++)
    tile[ty + i*8][tx] = src[(size_t)(kb + ty + i*8)*D_MODEL + nb + tx];
  __syncthreads();
  u16* dst = (z<3) ? (wqkv_t + (size_t)z*D_MODEL*D_MODEL) : wo_t;
  #pragma unroll
  for (int i=0;i<4;i++) {
    int n = nb + ty + i*8, k = kb + tx;
    dst[(size_t)n*D_MODEL + k] = f2bf(tile[tx][ty + i*8]);
  }
}

// ---------------- prep: pack mask to bits ----------------
__global__ __launch_bounds__(256) void k_maskpack(const int* __restrict__ mask,
                                                  unsigned long long* __restrict__ mb) {
  const int wid = blockIdx.x*4 + (threadIdx.x >> 6);   // 0..4095
  const int lane = threadIdx.x & 63;
  for (int t2 = 0; t2 < 32; ++t2) {
    int word = wid*32 + t2;                 // 0..131071
    int row = word >> 5;                    // b*SEQ + i
    int kb = word & 31;
    int m = mask[(size_t)row*SEQ + kb*64 + lane];
    unsigned long long bits = __ballot(m != 0);
    if (lane == 0) mb[word] = bits;
  }
}

// ---------------- prep: V [bh][L][64] -> Vt [bh][64][L] ----------------
__global__ __launch_bounds__(256) void k_vtrans(const u16* __restrict__ V, u16* __restrict__ Vt) {
  __shared__ u16 tile[64][72];
  const int bh = blockIdx.x >> 5;
  const int l0 = (blockIdx.x & 31) * 64;
  const int t = threadIdx.x;
  const u16* src = V + ((size_t)bh*SEQ + l0)*DK;
  #pragma unroll
  for (int j=0;j<2;j++) {
    int idx = t + j*256;                 // 0..511
    int r = idx >> 3, c8 = (idx & 7)*8;
    *(u16x8*)&tile[r][c8] = *(const u16x8*)(src + (size_t)r*DK + c8);
  }
  __syncthreads();
  u16* dst = Vt + (size_t)bh*DK*SEQ + l0;
  #pragma unroll
  for (int j=0;j<2;j++) {
    int idx = t + j*256;
    int d = idx >> 3, k8 = (idx & 7)*8;
    u16x8 o;
    #pragma unroll
    for (int e=0;e<8;e++) o[e] = tile[k8 + e][d];
    *(u16x8*)(dst + (size_t)d*SEQ + k8) = o;
  }
}

// ---------------- 128x128 MFMA GEMM, C = A @ Bt^T (+epilogue) ----------------
template<int EPI>
__global__ __launch_bounds__(256) void k_gemm(const u16* __restrict__ A, const u16* __restrict__ Bt,
                                              const int M, const int N, const int K, const int nbm,
                                              const float* __restrict__ bq, const float* __restrict__ bk,
                                              const float* __restrict__ bv,
                                              u16* __restrict__ Qo, u16* __restrict__ Ko, u16* __restrict__ Vo,
                                              const float* __restrict__ bo, float* __restrict__ out) {
  __shared__ u16 As[128*32];
  __shared__ u16 Bs[128*32];
  const int t = threadIdx.x, lane = t & 63, w = t >> 6;
  const int bm = blockIdx.x % nbm, bn = blockIdx.x / nbm;
  const int brow = bm*128, bcol = bn*128;

  const int srow = w*32 + (lane >> 2);
  const int sswz = (lane & 3) ^ ((lane >> 2) & 3);
  const u16* aS0 = A  + (size_t)(brow + srow)*K + sswz*8;
  const u16* aS1 = aS0 + (size_t)16*K;
  const u16* bS0 = Bt + (size_t)(bcol + srow)*K + sswz*8;
  const u16* bS1 = bS0 + (size_t)16*K;
  u16* aD0 = As + w*1024; u16* aD1 = aD0 + 512;
  u16* bD0 = Bs + w*1024; u16* bD1 = bD0 + 512;

  const int wr = w >> 1, wc = w & 1;
  const int slotA = (lane >> 4) ^ (lane & 3);
  const u16* aRd = As + (wr*64 + (lane & 15))*32 + slotA*8;
  const u16* bRd = Bs + (wc*64 + (lane & 15))*32 + slotA*8;

  f32x4 acc[4][4];
  #pragma unroll
  for (int i=0;i<4;i++)
    #pragma unroll
    for (int j=0;j<4;j++) acc[i][j] = (f32x4){0.f,0.f,0.f,0.f};

  for (int kt = 0; kt < K; kt += 32) {
    gl_lds16(aS0 + kt, aD0);
    gl_lds16(aS1 + kt, aD1);
    gl_lds16(bS0 + kt, bD0);
    gl_lds16(bS1 + kt, bD1);
    __syncthreads();
    bf16x8 af[4], bfr[4];
    #pragma unroll
    for (int m=0;m<4;m++) af[m] = ld_frag(aRd + m*512);
    #pragma unroll
    for (int n=0;n<4;n++) bfr[n] = ld_frag(bRd + n*512);
    #pragma unroll
    for (int m=0;m<4;m++)
      #pragma unroll
      for (int n=0;n<4;n++)
        acc[m][n] = __builtin_amdgcn_mfma_f32_16x16x32_bf16(af[m], bfr[n], acc[m][n], 0,0,0);
    __syncthreads();
  }

  const int orow = brow + wr*64 + (lane >> 4)*4;
  const int ocol = bcol + wc*64 + (lane & 15);
  if (EPI == 0) {
    const int mat = ocol >> 10;
    const float* bias = (mat==0) ? bq : (mat==1) ? bk : bv;
    u16* outp = (mat==0) ? Qo : (mat==1) ? Ko : Vo;
    // fold 1/sqrt(dk) AND log2(e) into Q so attention softmax runs in exp2 domain
    const float scal = (mat==0) ? 0.125f*1.4426950408889634f : 1.0f;
    #pragma unroll
    for (int m=0;m<4;m++) {
      #pragma unroll
      for (int n=0;n<4;n++) {
        int col = ocol + n*16;
        int c = col & 1023;
        float bb = bias[c];
        int h = c >> 6, d = c & 63;
        #pragma unroll
        for (int j=0;j<4;j++) {
          int row = orow + m*16 + j;
          int b = row >> 11, l = row & 2047;
          float v = (acc[m][n][j] + bb) * scal;
          outp[(((size_t)(b*NHEAD + h)*SEQ + l) << 6) + d] = f2bf(v);
        }
      }
    }
  } else {
    #pragma unroll
    for (int m=0;m<4;m++)
      #pragma unroll
      for (int n=0;n<4;n++) {
        int col = ocol + n*16;
        float bb = bo[col];
        #pragma unroll
        for (int j=0;j<4;j++) {
          int row = orow + m*16 + j;
          out[(size_t)row*N + col] = acc[m][n][j] + bb;
        }
      }
  }
}

// ---------------- flash attention: 8-wave KV-split, Q in LDS, KV dbuf ----------------
// Block: 512 thr = 8 waves. Half hf=w>>2 owns KV tiles [hf*16, hf*16+16).
// Q (128 rows x 64d, XOR-swizzled) staged once in LDS -> qf re-read per sub-tile,
// freeing 16 persistent arch-VGPRs (R5 spill root cause: 64-VGPR arch budget at
// 4 waves/SIMD). One f32x16 S live at a time (32-key subtiles).
__global__ __launch_bounds__(512, 4) void k_attn(const u16* __restrict__ Q, const u16* __restrict__ K,
                                                 const u16* __restrict__ Vt,
                                                 const unsigned long long* __restrict__ MB,
                                                 u16* __restrict__ AO) {
  __shared__ char smem[81920];   // [0,64K): KV dbuf (2 bufs x 2 halves x 16KB); [64K,80K): Q
  const int t = threadIdx.x, lane = t & 63, w = t >> 6;
  const int hf = w >> 2, widx = w & 3;
  // XCD-aware bijective swizzle: 512 blocks = 8 XCD x 64
  const int bid = blockIdx.x;
  const int swz = (bid & 7)*64 + (bid >> 3);
  const int bh = swz >> 4;
  const int q0 = (swz & 15) * 128;
  const int b = bh >> 4, h = bh & 15;
  const int lq = lane & 31, hi = lane >> 5, l7 = lane & 7;

  const int qg = q0 + widx*32 + lq;

  // staging geometry (shared by Q and KV): lane covers row (lane>>3), 16B slot (lane&7)
  const int sswz = l7 ^ ((lane >> 3) & 7);        // pre-swizzled global source slot
  const int srow = widx*16 + (lane >> 3);         // KV: within-half row
  const u16* kSb = K  + ((size_t)bh*SEQ + srow)*DK + sswz*8;
  const u16* vSb = Vt + ((size_t)bh*DK + srow)*SEQ + sswz*8;

  // Q staging: wave w covers block-q rows w*16..w*16+15
  u16* qlds = (u16*)(smem + 65536);
  {
    const int qsrow = w*16 + (lane >> 3);
    const u16* qS = Q + ((size_t)bh*SEQ + q0 + qsrow)*DK + sswz*8;
    gl_lds16(qS, qlds + w*1024);
    gl_lds16(qS + 8*DK, qlds + w*1024 + 512);
  }
  const u16* qrd = qlds + (widx*32 + lq)*64;      // this lane's q row base (swizzled slots)

  f32x16 o0 = 0.f, o1 = 0.f;
  float m_run = -1e30f, l_run = 0.f;
  const unsigned long long* mbp = MB + ((size_t)b*SEQ + qg)*32;

  #define STAGE(buf, tile) do {                                           \
    const u16* kp_ = kSb + (size_t)(tile)*64*DK;                          \
    const u16* vp_ = vSb + (size_t)(tile)*64;                             \
    u16* kd_ = (u16*)(smem + (buf)*32768 + hf*16384) + widx*1024;         \
    u16* vd_ = (u16*)(smem + (buf)*32768 + hf*16384 + 8192) + widx*1024;  \
    gl_lds16(kp_, kd_); gl_lds16(kp_ + 8*DK, kd_ + 512);                  \
    gl_lds16(vp_, vd_); gl_lds16(vp_ + 8*SEQ, vd_ + 512);                 \
  } while (0)

  STAGE(0, hf*16);
  asm volatile("s_waitcnt vmcnt(0)" ::: "memory");
  __builtin_amdgcn_s_barrier();

  for (int i = 0; i < 16; ++i) {
    const int cur = i & 1;
    if (i + 1 < 16) STAGE(cur ^ 1, hf*16 + i + 1);   // in flight across compute
    const u16* Kbuf = (const u16*)(smem + cur*32768 + hf*16384);
    const u16* Vbuf = (const u16*)(smem + cur*32768 + hf*16384 + 8192);
    const unsigned long long mb = mbp[hf*16 + i];
    const bool full = __all(mb == ~0ull);

    #pragma unroll
    for (int sub = 0; sub < 2; ++sub) {
      // ---- S^T for 32 keys (Q frags re-read from LDS; conflict-free XOR slots) ----
      f32x16 s = 0.f;
      __builtin_amdgcn_s_setprio(1);
      #pragma unroll
      for (int ks=0;ks<4;ks++) {
        const int ph = (ks*2 + hi) ^ l7;
        bf16x8 kf = ld_frag(Kbuf + (sub*32 + lq)*64 + ph*8);
        bf16x8 qf = ld_frag(qrd + ph*8);
        s = __builtin_amdgcn_mfma_f32_32x32x16_bf16(kf, qf, s, 0,0,0);
      }
      __builtin_amdgcn_s_setprio(0);

      if (!full) {
        #pragma unroll
        for (int r=0;r<16;r++) {
          int kl = sub*32 + (r&3) + 8*(r>>2) + 4*hi;
          if (!((mb >> kl) & 1ull)) s[r] = -1e9f;
        }
      }

      // ---- online softmax (tree reduce), defer-max THR=8 (exp2 domain) ----
      float tm[8];
      #pragma unroll
      for (int r=0;r<8;r++) tm[r] = fmaxf(s[r], s[8+r]);
      #pragma unroll
      for (int st=4; st>0; st>>=1)
        #pragma unroll
        for (int r=0;r<4;r++) if (r < st) tm[r] = fmaxf(tm[r], tm[r+st]);
      float mx = fmaxf(tm[0], __shfl_xor(tm[0], 32));
      if (!__all(mx <= m_run + 8.0f)) {
        float m_new = fmaxf(m_run, mx);
        float corr = __builtin_amdgcn_exp2f(m_run - m_new);
        l_run *= corr;
        #pragma unroll
        for (int r=0;r<16;r++) { o0[r] *= corr; o1[r] *= corr; }
        m_run = m_new;
      }
      #pragma unroll
      for (int r=0;r<16;r++) s[r] = __builtin_amdgcn_exp2f(s[r] - m_run);
      float ts[8];
      #pragma unroll
      for (int r=0;r<8;r++) ts[r] = s[r] + s[8+r];
      #pragma unroll
      for (int st=4; st>0; st>>=1)
        #pragma unroll
        for (int r=0;r<4;r++) if (r < st) ts[r] += ts[r+st];
      l_run += ts[0] + __shfl_xor(ts[0], 32);

      // ---- P -> bf16 PA frags (cvt_pk + permlane32_swap); PV (V 2-frags at a time) ----
      u32 w0 = cvtpk(s[0],  s[1]),  w1 = cvtpk(s[2],  s[3]);
      u32 w2 = cvtpk(s[4],  s[5]),  w3 = cvtpk(s[6],  s[7]);
      u32 w4 = cvtpk(s[8],  s[9]),  w5 = cvtpk(s[10], s[11]);
      u32 w6 = cvtpk(s[12], s[13]), w7 = cvtpk(s[14], s[15]);
      asm volatile("v_permlane32_swap_b32 %0, %1" : "+v"(w0), "+v"(w2));
      asm volatile("v_permlane32_swap_b32 %0, %1" : "+v"(w1), "+v"(w3));
      asm volatile("v_permlane32_swap_b32 %0, %1" : "+v"(w4), "+v"(w6));
      asm volatile("v_permlane32_swap_b32 %0, %1" : "+v"(w5), "+v"(w7));
      bf16x8 pa0 = __builtin_bit_cast(bf16x8, (u32x4){w0, w1, w2, w3});
      bf16x8 pa1 = __builtin_bit_cast(bf16x8, (u32x4){w4, w5, w6, w7});
      const int ph0 = ((sub*2+0)*2 + hi) ^ l7;
      const int ph1 = ((sub*2+1)*2 + hi) ^ l7;
      {
        bf16x8 v00 = ld_frag(Vbuf + lq*64 + ph0*8);
        bf16x8 v01 = ld_frag(Vbuf + lq*64 + ph1*8);
        __builtin_amdgcn_s_setprio(1);
        o0 = __builtin_amdgcn_mfma_f32_32x32x16_bf16(v00, pa0, o0, 0,0,0);
        o0 = __builtin_amdgcn_mfma_f32_32x32x16_bf16(v01, pa1, o0, 0,0,0);
        __builtin_amdgcn_s_setprio(0);
      }
      {
        bf16x8 v10 = ld_frag(Vbuf + (32+lq)*64 + ph0*8);
        bf16x8 v11 = ld_frag(Vbuf + (32+lq)*64 + ph1*8);
        __builtin_amdgcn_s_setprio(1);
        o1 = __builtin_amdgcn_mfma_f32_32x32x16_bf16(v10, pa0, o1, 0,0,0);
        o1 = __builtin_amdgcn_mfma_f32_32x32x16_bf16(v11, pa1, o1, 0,0,0);
        __builtin_amdgcn_s_setprio(0);
      }
    }

    asm volatile("s_waitcnt vmcnt(0)" ::: "memory");  // next tile landed (hidden under compute)
    __builtin_amdgcn_s_barrier();
  }
  #undef STAGE

  // ---- merge halves via LDS (stride-35 f32 slots: conflict-free; reuses KV area) ----
  float* marea = (float*)smem;
  if (hf == 1) {
    float* p = marea + (size_t)(widx*64 + lane)*35;
    #pragma unroll
    for (int r=0;r<16;r++) { p[r] = o0[r]; p[16+r] = o1[r]; }
    p[32] = m_run; p[33] = l_run;
  }
  __syncthreads();
  if (hf == 0) {
    const float* p = marea + (size_t)(widx*64 + lane)*35;
    float m1 = p[32], l1 = p[33];
    float mm = fmaxf(m_run, m1);
    float c0 = __builtin_amdgcn_exp2f(m_run - mm);
    float c1 = __builtin_amdgcn_exp2f(m1 - mm);
    float inv = 1.0f / (l_run*c0 + l1*c1);
    size_t base = ((size_t)(b*SEQ + qg))*D_MODEL + h*DK;
    u16x4 g;
    #pragma unroll
    for (int rr=0;rr<4;rr++) {
      #pragma unroll
      for (int i2=0;i2<4;i2++) g[i2] = f2bf((o0[rr*4+i2]*c0 + p[rr*4+i2]*c1) * inv);
      *(u16x4*)(AO + base + rr*8 + hi*4) = g;
    }
    #pragma unroll
    for (int rr=0;rr<4;rr++) {
      #pragma unroll
      for (int i2=0;i2<4;i2++) g[i2] = f2bf((o1[rr*4+i2]*c0 + p[16+rr*4+i2]*c1) * inv);
      *(u16x4*)(AO + base + 32 + rr*8 + hi*4) = g;
    }
  }
}

extern "C" void kernel_launch(void* const* d_in, const int* in_sizes, int n_in,
                              void* d_out, int out_size, void* d_ws, size_t ws_size,
                              hipStream_t stream) {
  const float* x  = (const float*)d_in[0];
  const int*  msk = (const int*)d_in[1];
  const float* wq = (const float*)d_in[2];
  const float* bq = (const float*)d_in[3];
  const float* wk = (const float*)d_in[4];
  const float* bk = (const float*)d_in[5];
  const float* wv = (const float*)d_in[6];
  const float* bv = (const float*)d_in[7];
  const float* wo = (const float*)d_in[8];
  const float* bo = (const float*)d_in[9];
  float* out = (float*)d_out;

  char* ws = (char*)d_ws;
  size_t off = 0;
  u16* Xb   = (u16*)(ws + off); off += (size_t)MTOT*D_MODEL*2;
  u16* Wqkv = (u16*)(ws + off); off += (size_t)3*D_MODEL*D_MODEL*2;
  u16* Wot  = (u16*)(ws + off); off += (size_t)D_MODEL*D_MODEL*2;
  u16* Qb   = (u16*)(ws + off); off += (size_t)BATCH*NHEAD*SEQ*DK*2;
  u16* Kb   = (u16*)(ws + off); off += (size_t)BATCH*NHEAD*SEQ*DK*2;
  u16* Vb   = (u16*)(ws + off); off += (size_t)BATCH*NHEAD*SEQ*DK*2;
  u16* Vtb  = (u16*)(ws + off); off += (size_t)BATCH*NHEAD*SEQ*DK*2;
  u16* AO   = (u16*)(ws + off); off += (size_t)MTOT*D_MODEL*2;
  unsigned long long* Mb = (unsigned long long*)(ws + off);

  k_cvt_x<<<MTOT*D_MODEL/4/256, 256, 0, stream>>>(x, Xb);
  k_wtrans<<<dim3(32,32,4), 256, 0, stream>>>(wq, wk, wv, wo, Wqkv, Wot);
  k_maskpack<<<1024, 256, 0, stream>>>(msk, Mb);
  k_gemm<0><<<(MTOT/128)*(3*D_MODEL/128), 256, 0, stream>>>(
      Xb, Wqkv, MTOT, 3*D_MODEL, D_MODEL, MTOT/128,
      bq, bk, bv, Qb, Kb, Vb, nullptr, nullptr);
  k_vtrans<<<BATCH*NHEAD*(SEQ/64), 256, 0, stream>>>(Vb, Vtb);
  k_attn<<<BATCH*NHEAD*(SEQ/128), 512, 0, stream>>>(Qb, Kb, Vtb, Mb, AO);
  k_gemm<1><<<(MTOT/128)*(D_MODEL/128), 256, 0, stream>>>(
      AO, Wot, MTOT, D_MODEL, D_MODEL, MTOT/128,
      nullptr, nullptr, nullptr, nullptr, nullptr, nullptr, bo, out);
}

// Round 7
// 148.304 us; speedup vs baseline: 1.3453x; 1.0034x over previous
//
#include <hip/hip_runtime.h>
#include <stdint.h>

#define D_MODEL 1024
#define NHEAD   16
#define DK      64
#define BATCH   2
#define SEQ     2048
#define MTOT    (BATCH*SEQ)   // 4096

typedef unsigned short u16;
typedef unsigned int   u32;
typedef u16    u16x4  __attribute__((ext_vector_type(4)));
typedef u16    u16x8  __attribute__((ext_vector_type(8)));
typedef u32    u32x4  __attribute__((ext_vector_type(4)));
typedef __bf16 bf16x8 __attribute__((ext_vector_type(8)));
typedef float  f32x4  __attribute__((ext_vector_type(4)));
typedef float  f32x16 __attribute__((ext_vector_type(16)));

__device__ __forceinline__ u16 f2bf(float f) {
  union { float f; unsigned u; } v; v.f = f;
  return (u16)((v.u + 0x7fffu + ((v.u >> 16) & 1u)) >> 16);
}

__device__ __forceinline__ void gl_lds16(const void* g, void* l) {
  __builtin_amdgcn_global_load_lds((const __attribute__((address_space(1))) void*)g,
                                   (__attribute__((address_space(3))) void*)l, 16, 0, 0);
}

__device__ __forceinline__ bf16x8 ld_frag(const u16* p) {
  return __builtin_bit_cast(bf16x8, *(const u16x8*)p);
}

__device__ __forceinline__ u32 cvtpk(float lo, float hi) {
  u32 r;
  asm("v_cvt_pk_bf16_f32 %0, %1, %2" : "=v"(r) : "v"(lo), "v"(hi));
  return r;
}

// ---------------- fused prep: x->bf16 | W->W^T bf16 | mask pack ----------------
// grid = 4096 (cvt_x) + 4096 (wtrans) + 1024 (maskpack) = 9216 blocks x 256 thr.
__global__ __launch_bounds__(256) void k_prep(const float* __restrict__ x, u16* __restrict__ xb,
                                              const float* __restrict__ wq, const float* __restrict__ wk,
                                              const float* __restrict__ wv, const float* __restrict__ wo,
                                              u16* __restrict__ wqkv_t, u16* __restrict__ wo_t,
                                              const int* __restrict__ mask,
                                              unsigned long long* __restrict__ mb) {
  const int bid = blockIdx.x;
  if (bid < 4096) {
    // ---- x -> bf16 ----
    int i = bid * 256 + threadIdx.x;
    const float4 v = ((const float4*)x)[i];
    u16x4 o; o[0]=f2bf(v.x); o[1]=f2bf(v.y); o[2]=f2bf(v.z); o[3]=f2bf(v.w);
    *(u16x4*)(xb + (size_t)i*4) = o;
  } else if (bid < 8192) {
    // ---- W -> W^T bf16 ----
    __shared__ float tile[32][33];
    const int idx = bid - 4096;
    const int z = idx >> 10;
    const float* src = (z==0)?wq:(z==1)?wk:(z==2)?wv:wo;
    const int kb = ((idx >> 5) & 31)*32, nb = (idx & 31)*32;
    const int tx = threadIdx.x & 31, ty = threadIdx.x >> 5;  // 32 x 8
    #pragma unroll
    for (int i=0;i<4;i++)
      tile[ty + i*8][tx] = src[(size_t)(kb + ty + i*8)*D_MODEL + nb + tx];
    __syncthreads();
    u16* dst = (z<3) ? (wqkv_t + (size_t)z*D_MODEL*D_MODEL) : wo_t;
    #pragma unroll
    for (int i=0;i<4;i++) {
      int n = nb + ty + i*8, k = kb + tx;
      dst[(size_t)n*D_MODEL + k] = f2bf(tile[tx][ty + i*8]);
    }
  } else {
    // ---- pack mask to bits ----
    const int wid = (bid - 8192)*4 + (threadIdx.x >> 6);   // 0..4095
    const int lane = threadIdx.x & 63;
    for (int t2 = 0; t2 < 32; ++t2) {
      int word = wid*32 + t2;                 // 0..131071
      int row = word >> 5;                    // b*SEQ + i
      int kb = word & 31;
      int m = mask[(size_t)row*SEQ + kb*64 + lane];
      unsigned long long bits = __ballot(m != 0);
      if (lane == 0) mb[word] = bits;
    }
  }
}

// ---------------- prep: V [bh][L][64] -> Vt [bh][64][L] ----------------
__global__ __launch_bounds__(256) void k_vtrans(const u16* __restrict__ V, u16* __restrict__ Vt) {
  __shared__ u16 tile[64][72];
  const int bh = blockIdx.x >> 5;
  const int l0 = (blockIdx.x & 31) * 64;
  const int t = threadIdx.x;
  const u16* src = V + ((size_t)bh*SEQ + l0)*DK;
  #pragma unroll
  for (int j=0;j<2;j++) {
    int idx = t + j*256;                 // 0..511
    int r = idx >> 3, c8 = (idx & 7)*8;
    *(u16x8*)&tile[r][c8] = *(const u16x8*)(src + (size_t)r*DK + c8);
  }
  __syncthreads();
  u16* dst = Vt + (size_t)bh*DK*SEQ + l0;
  #pragma unroll
  for (int j=0;j<2;j++) {
    int idx = t + j*256;
    int d = idx >> 3, k8 = (idx & 7)*8;
    u16x8 o;
    #pragma unroll
    for (int e=0;e<8;e++) o[e] = tile[k8 + e][d];
    *(u16x8*)(dst + (size_t)d*SEQ + k8) = o;
  }
}

// ---------------- 128x128 MFMA GEMM, C = A @ Bt^T (+epilogue) ----------------
template<int EPI>
__global__ __launch_bounds__(256) void k_gemm(const u16* __restrict__ A, const u16* __restrict__ Bt,
                                              const int M, const int N, const int K, const int nbm,
                                              const float* __restrict__ bq, const float* __restrict__ bk,
                                              const float* __restrict__ bv,
                                              u16* __restrict__ Qo, u16* __restrict__ Ko, u16* __restrict__ Vo,
                                              const float* __restrict__ bo, float* __restrict__ out) {
  __shared__ u16 As[128*32];
  __shared__ u16 Bs[128*32];
  const int t = threadIdx.x, lane = t & 63, w = t >> 6;
  // XCD-aware bijective swizzle (gridDim.x % 8 == 0 for all our shapes)
  const int cpx = gridDim.x >> 3;
  const int bswz = (blockIdx.x & 7)*cpx + (blockIdx.x >> 3);
  const int bm = bswz % nbm, bn = bswz / nbm;
  const int brow = bm*128, bcol = bn*128;

  const int srow = w*32 + (lane >> 2);
  const int sswz = (lane & 3) ^ ((lane >> 2) & 3);
  const u16* aS0 = A  + (size_t)(brow + srow)*K + sswz*8;
  const u16* aS1 = aS0 + (size_t)16*K;
  const u16* bS0 = Bt + (size_t)(bcol + srow)*K + sswz*8;
  const u16* bS1 = bS0 + (size_t)16*K;
  u16* aD0 = As + w*1024; u16* aD1 = aD0 + 512;
  u16* bD0 = Bs + w*1024; u16* bD1 = bD0 + 512;

  const int wr = w >> 1, wc = w & 1;
  const int slotA = (lane >> 4) ^ (lane & 3);
  const u16* aRd = As + (wr*64 + (lane & 15))*32 + slotA*8;
  const u16* bRd = Bs + (wc*64 + (lane & 15))*32 + slotA*8;

  f32x4 acc[4][4];
  #pragma unroll
  for (int i=0;i<4;i++)
    #pragma unroll
    for (int j=0;j<4;j++) acc[i][j] = (f32x4){0.f,0.f,0.f,0.f};

  for (int kt = 0; kt < K; kt += 32) {
    gl_lds16(aS0 + kt, aD0);
    gl_lds16(aS1 + kt, aD1);
    gl_lds16(bS0 + kt, bD0);
    gl_lds16(bS1 + kt, bD1);
    __syncthreads();
    bf16x8 af[4], bfr[4];
    #pragma unroll
    for (int m=0;m<4;m++) af[m] = ld_frag(aRd + m*512);
    #pragma unroll
    for (int n=0;n<4;n++) bfr[n] = ld_frag(bRd + n*512);
    #pragma unroll
    for (int m=0;m<4;m++)
      #pragma unroll
      for (int n=0;n<4;n++)
        acc[m][n] = __builtin_amdgcn_mfma_f32_16x16x32_bf16(af[m], bfr[n], acc[m][n], 0,0,0);
    __syncthreads();
  }

  const int orow = brow + wr*64 + (lane >> 4)*4;
  const int ocol = bcol + wc*64 + (lane & 15);
  if (EPI == 0) {
    const int mat = ocol >> 10;
    const float* bias = (mat==0) ? bq : (mat==1) ? bk : bv;
    u16* outp = (mat==0) ? Qo : (mat==1) ? Ko : Vo;
    // fold 1/sqrt(dk) AND log2(e) into Q so attention softmax runs in exp2 domain
    const float scal = (mat==0) ? 0.125f*1.4426950408889634f : 1.0f;
    #pragma unroll
    for (int m=0;m<4;m++) {
      #pragma unroll
      for (int n=0;n<4;n++) {
        int col = ocol + n*16;
        int c = col & 1023;
        float bb = bias[c];
        int h = c >> 6, d = c & 63;
        #pragma unroll
        for (int j=0;j<4;j++) {
          int row = orow + m*16 + j;
          int b = row >> 11, l = row & 2047;
          float v = (acc[m][n][j] + bb) * scal;
          outp[(((size_t)(b*NHEAD + h)*SEQ + l) << 6) + d] = f2bf(v);
        }
      }
    }
  } else {
    #pragma unroll
    for (int m=0;m<4;m++)
      #pragma unroll
      for (int n=0;n<4;n++) {
        int col = ocol + n*16;
        float bb = bo[col];
        #pragma unroll
        for (int j=0;j<4;j++) {
          int row = orow + m*16 + j;
          out[(size_t)row*N + col] = acc[m][n][j] + bb;
        }
      }
  }
}

// ---------------- flash attention: 8-wave KV-split, Q in LDS, KV dbuf, MFMA l-sum ----
// Block: 512 thr = 8 waves. Half hf=w>>2 owns KV tiles [hf*16, hf*16+16).
// l computed via lacc = mfma(ones, P^T): every lane's lacc[0] = its q's running sum
// (all rows of ones*P^T equal the column sum; both hi-halves identical -> no shfl).
// AGPR budget: o0+o1+s+lacc = 64 exactly at 4 waves/SIMD.
__global__ __launch_bounds__(512, 4) void k_attn(const u16* __restrict__ Q, const u16* __restrict__ K,
                                                 const u16* __restrict__ Vt,
                                                 const unsigned long long* __restrict__ MB,
                                                 u16* __restrict__ AO) {
  __shared__ char smem[81920];   // [0,64K): KV dbuf (2 bufs x 2 halves x 16KB); [64K,80K): Q
  const int t = threadIdx.x, lane = t & 63, w = t >> 6;
  const int hf = w >> 2, widx = w & 3;
  // XCD-aware bijective swizzle: 512 blocks = 8 XCD x 64
  const int bid = blockIdx.x;
  const int swz = (bid & 7)*64 + (bid >> 3);
  const int bh = swz >> 4;
  const int q0 = (swz & 15) * 128;
  const int b = bh >> 4, h = bh & 15;
  const int lq = lane & 31, hi = lane >> 5, l7 = lane & 7;

  const int qg = q0 + widx*32 + lq;

  // staging geometry (shared by Q and KV): lane covers row (lane>>3), 16B slot (lane&7)
  const int sswz = l7 ^ ((lane >> 3) & 7);        // pre-swizzled global source slot
  const int srow = widx*16 + (lane >> 3);         // KV: within-half row
  const u16* kSb = K  + ((size_t)bh*SEQ + srow)*DK + sswz*8;
  const u16* vSb = Vt + ((size_t)bh*DK + srow)*SEQ + sswz*8;

  // Q staging: wave w covers block-q rows w*16..w*16+15
  u16* qlds = (u16*)(smem + 65536);
  {
    const int qsrow = w*16 + (lane >> 3);
    const u16* qS = Q + ((size_t)bh*SEQ + q0 + qsrow)*DK + sswz*8;
    gl_lds16(qS, qlds + w*1024);
    gl_lds16(qS + 8*DK, qlds + w*1024 + 512);
  }
  const u16* qrd = qlds + (widx*32 + lq)*64;      // this lane's q row base (swizzled slots)

  u16x8 ones8;
  #pragma unroll
  for (int i=0;i<8;i++) ones8[i] = 0x3F80;        // bf16 1.0
  const bf16x8 ones = __builtin_bit_cast(bf16x8, ones8);

  f32x16 o0 = 0.f, o1 = 0.f, lacc = 0.f;
  float m_run = -1e30f;
  const unsigned long long* mbp = MB + ((size_t)b*SEQ + qg)*32;

  #define STAGE(buf, tile) do {                                           \
    const u16* kp_ = kSb + (size_t)(tile)*64*DK;                          \
    const u16* vp_ = vSb + (size_t)(tile)*64;                             \
    u16* kd_ = (u16*)(smem + (buf)*32768 + hf*16384) + widx*1024;         \
    u16* vd_ = (u16*)(smem + (buf)*32768 + hf*16384 + 8192) + widx*1024;  \
    gl_lds16(kp_, kd_); gl_lds16(kp_ + 8*DK, kd_ + 512);                  \
    gl_lds16(vp_, vd_); gl_lds16(vp_ + 8*SEQ, vd_ + 512);                 \
  } while (0)

  STAGE(0, hf*16);
  asm volatile("s_waitcnt vmcnt(0)" ::: "memory");
  __builtin_amdgcn_s_barrier();

  for (int i = 0; i < 16; ++i) {
    const int cur = i & 1;
    if (i + 1 < 16) STAGE(cur ^ 1, hf*16 + i + 1);   // in flight across compute
    const u16* Kbuf = (const u16*)(smem + cur*32768 + hf*16384);
    const u16* Vbuf = (const u16*)(smem + cur*32768 + hf*16384 + 8192);
    const unsigned long long mb = mbp[hf*16 + i];
    const bool full = __all(mb == ~0ull);

    #pragma unroll
    for (int sub = 0; sub < 2; ++sub) {
      // ---- S^T for 32 keys (Q frags re-read from LDS; conflict-free XOR slots) ----
      f32x16 s = 0.f;
      __builtin_amdgcn_s_setprio(1);
      #pragma unroll
      for (int ks=0;ks<4;ks++) {
        const int ph = (ks*2 + hi) ^ l7;
        bf16x8 kf = ld_frag(Kbuf + (sub*32 + lq)*64 + ph*8);
        bf16x8 qf = ld_frag(qrd + ph*8);
        s = __builtin_amdgcn_mfma_f32_32x32x16_bf16(kf, qf, s, 0,0,0);
      }
      __builtin_amdgcn_s_setprio(0);

      if (!full) {
        #pragma unroll
        for (int r=0;r<16;r++) {
          int kl = sub*32 + (r&3) + 8*(r>>2) + 4*hi;
          if (!((mb >> kl) & 1ull)) s[r] = -1e9f;
        }
      }

      // ---- online softmax: fmax chain (-> v_max3), defer-max THR=8 (exp2 domain) ----
      float mx = fmaxf(s[0], s[1]);
      #pragma unroll
      for (int r=2;r<16;r++) mx = fmaxf(mx, s[r]);
      mx = fmaxf(mx, __shfl_xor(mx, 32));
      if (!__all(mx <= m_run + 8.0f)) {
        float m_new = fmaxf(m_run, mx);
        float corr = __builtin_amdgcn_exp2f(m_run - m_new);
        lacc[0] *= corr;
        #pragma unroll
        for (int r=0;r<16;r++) { o0[r] *= corr; o1[r] *= corr; }
        m_run = m_new;
      }
      #pragma unroll
      for (int r=0;r<16;r++) s[r] = __builtin_amdgcn_exp2f(s[r] - m_run);

      // ---- P -> bf16 PA frags (cvt_pk + permlane32_swap); PV + MFMA l-sum ----
      u32 w0 = cvtpk(s[0],  s[1]),  w1 = cvtpk(s[2],  s[3]);
      u32 w2 = cvtpk(s[4],  s[5]),  w3 = cvtpk(s[6],  s[7]);
      u32 w4 = cvtpk(s[8],  s[9]),  w5 = cvtpk(s[10], s[11]);
      u32 w6 = cvtpk(s[12], s[13]), w7 = cvtpk(s[14], s[15]);
      asm volatile("v_permlane32_swap_b32 %0, %1" : "+v"(w0), "+v"(w2));
      asm volatile("v_permlane32_swap_b32 %0, %1" : "+v"(w1), "+v"(w3));
      asm volatile("v_permlane32_swap_b32 %0, %1" : "+v"(w4), "+v"(w6));
      asm volatile("v_permlane32_swap_b32 %0, %1" : "+v"(w5), "+v"(w7));
      bf16x8 pa0 = __builtin_bit_cast(bf16x8, (u32x4){w0, w1, w2, w3});
      bf16x8 pa1 = __builtin_bit_cast(bf16x8, (u32x4){w4, w5, w6, w7});
      const int ph0 = ((sub*2+0)*2 + hi) ^ l7;
      const int ph1 = ((sub*2+1)*2 + hi) ^ l7;
      {
        bf16x8 v00 = ld_frag(Vbuf + lq*64 + ph0*8);
        bf16x8 v01 = ld_frag(Vbuf + lq*64 + ph1*8);
        __builtin_amdgcn_s_setprio(1);
        o0 = __builtin_amdgcn_mfma_f32_32x32x16_bf16(v00, pa0, o0, 0,0,0);
        o0 = __builtin_amdgcn_mfma_f32_32x32x16_bf16(v01, pa1, o0, 0,0,0);
        __builtin_amdgcn_s_setprio(0);
      }
      {
        bf16x8 v10 = ld_frag(Vbuf + (32+lq)*64 + ph0*8);
        bf16x8 v11 = ld_frag(Vbuf + (32+lq)*64 + ph1*8);
        __builtin_amdgcn_s_setprio(1);
        o1 = __builtin_amdgcn_mfma_f32_32x32x16_bf16(v10, pa0, o1, 0,0,0);
        o1 = __builtin_amdgcn_mfma_f32_32x32x16_bf16(v11, pa1, o1, 0,0,0);
        lacc = __builtin_amdgcn_mfma_f32_32x32x16_bf16(ones, pa0, lacc, 0,0,0);
        lacc = __builtin_amdgcn_mfma_f32_32x32x16_bf16(ones, pa1, lacc, 0,0,0);
        __builtin_amdgcn_s_setprio(0);
      }
    }

    asm volatile("s_waitcnt vmcnt(0)" ::: "memory");  // next tile landed (hidden under compute)
    __builtin_amdgcn_s_barrier();
  }
  #undef STAGE

  // ---- merge halves via LDS (stride-35 f32 slots: conflict-free; reuses KV area) ----
  const float l_run = lacc[0];
  float* marea = (float*)smem;
  if (hf == 1) {
    float* p = marea + (size_t)(widx*64 + lane)*35;
    #pragma unroll
    for (int r=0;r<16;r++) { p[r] = o0[r]; p[16+r] = o1[r]; }
    p[32] = m_run; p[33] = l_run;
  }
  __syncthreads();
  if (hf == 0) {
    const float* p = marea + (size_t)(widx*64 + lane)*35;
    float m1 = p[32], l1 = p[33];
    float mm = fmaxf(m_run, m1);
    float c0 = __builtin_amdgcn_exp2f(m_run - mm);
    float c1 = __builtin_amdgcn_exp2f(m1 - mm);
    float inv = 1.0f / (l_run*c0 + l1*c1);
    size_t base = ((size_t)(b*SEQ + qg))*D_MODEL + h*DK;
    u16x4 g;
    #pragma unroll
    for (int rr=0;rr<4;rr++) {
      #pragma unroll
      for (int i2=0;i2<4;i2++) g[i2] = f2bf((o0[rr*4+i2]*c0 + p[rr*4+i2]*c1) * inv);
      *(u16x4*)(AO + base + rr*8 + hi*4) = g;
    }
    #pragma unroll
    for (int rr=0;rr<4;rr++) {
      #pragma unroll
      for (int i2=0;i2<4;i2++) g[i2] = f2bf((o1[rr*4+i2]*c0 + p[16+rr*4+i2]*c1) * inv);
      *(u16x4*)(AO + base + 32 + rr*8 + hi*4) = g;
    }
  }
}

extern "C" void kernel_launch(void* const* d_in, const int* in_sizes, int n_in,
                              void* d_out, int out_size, void* d_ws, size_t ws_size,
                              hipStream_t stream) {
  const float* x  = (const float*)d_in[0];
  const int*  msk = (const int*)d_in[1];
  const float* wq = (const float*)d_in[2];
  const float* bq = (const float*)d_in[3];
  const float* wk = (const float*)d_in[4];
  const float* bk = (const float*)d_in[5];
  const float* wv = (const float*)d_in[6];
  const float* bv = (const float*)d_in[7];
  const float* wo = (const float*)d_in[8];
  const float* bo = (const float*)d_in[9];
  float* out = (float*)d_out;

  char* ws = (char*)d_ws;
  size_t off = 0;
  u16* Xb   = (u16*)(ws + off); off += (size_t)MTOT*D_MODEL*2;
  u16* Wqkv = (u16*)(ws + off); off += (size_t)3*D_MODEL*D_MODEL*2;
  u16* Wot  = (u16*)(ws + off); off += (size_t)D_MODEL*D_MODEL*2;
  u16* Qb   = (u16*)(ws + off); off += (size_t)BATCH*NHEAD*SEQ*DK*2;
  u16* Kb   = (u16*)(ws + off); off += (size_t)BATCH*NHEAD*SEQ*DK*2;
  u16* Vb   = (u16*)(ws + off); off += (size_t)BATCH*NHEAD*SEQ*DK*2;
  u16* Vtb  = (u16*)(ws + off); off += (size_t)BATCH*NHEAD*SEQ*DK*2;
  u16* AO   = (u16*)(ws + off); off += (size_t)MTOT*D_MODEL*2;
  unsigned long long* Mb = (unsigned long long*)(ws + off);

  k_prep<<<9216, 256, 0, stream>>>(x, Xb, wq, wk, wv, wo, Wqkv, Wot, msk, Mb);
  k_gemm<0><<<(MTOT/128)*(3*D_MODEL/128), 256, 0, stream>>>(
      Xb, Wqkv, MTOT, 3*D_MODEL, D_MODEL, MTOT/128,
      bq, bk, bv, Qb, Kb, Vb, nullptr, nullptr);
  k_vtrans<<<BATCH*NHEAD*(SEQ/64), 256, 0, stream>>>(Vb, Vtb);
  k_attn<<<BATCH*NHEAD*(SEQ/128), 512, 0, stream>>>(Qb, Kb, Vtb, Mb, AO);
  k_gemm<1><<<(MTOT/128)*(D_MODEL/128), 256, 0, stream>>>(
      AO, Wot, MTOT, D_MODEL, D_MODEL, MTOT/128,
      nullptr, nullptr, nullptr, nullptr, nullptr, nullptr, bo, out);
}